// Round 1
// baseline (3363.098 us; speedup 1.0000x reference)
//
#include <hip/hip_runtime.h>
#include <math.h>

#define CH 256

// ---------------- utility kernels ----------------

__global__ void fill_zero4(float4* __restrict__ p, size_t n4) {
  size_t i = (size_t)blockIdx.x * blockDim.x + threadIdx.x;
  size_t st = (size_t)gridDim.x * blockDim.x;
  float4 z = make_float4(0.f, 0.f, 0.f, 0.f);
  for (; i < n4; i += st) p[i] = z;
}

__global__ void scatter_edges(const int* __restrict__ ei, int E, int n, float* __restrict__ A) {
  int e = blockIdx.x * blockDim.x + threadIdx.x;
  if (e < E) atomicAdd(&A[(size_t)ei[e] * n + ei[E + e]], 1.0f);
}

// where(diag != 0, diag, 2.0)
__global__ void diag_fix(float* __restrict__ A, int n) {
  int i = blockIdx.x * blockDim.x + threadIdx.x;
  if (i < n) { size_t id = (size_t)i * n + i; if (A[id] == 0.f) A[id] = 2.0f; }
}

__global__ void diag_set(float* __restrict__ A, int n, float v) {
  int i = blockIdx.x * blockDim.x + threadIdx.x;
  if (i < n) A[(size_t)i * n + i] = v;
}

// deg[i] = sum_j A[j,i]; dinv = deg>0 ? rsqrt(deg) : 0  (column sums)
__global__ void col_deg_dinv(const float* __restrict__ A, int n, float* __restrict__ dinv) {
  int i = blockIdx.x * blockDim.x + threadIdx.x;
  if (i >= n) return;
  float s = 0.f;
  for (int j = 0; j < n; ++j) s += A[(size_t)j * n + i];
  dinv[i] = (s > 0.f) ? 1.0f / sqrtf(s) : 0.f;
}

// score[i] = tanh(dot(x[i,:], p) / ||p||), one wave per node
__global__ void node_scores(const float* __restrict__ x, const float* __restrict__ p,
                            int n, float* __restrict__ sc) {
  int wave = threadIdx.x >> 6;
  int lane = threadIdx.x & 63;
  int node = blockIdx.x * 4 + wave;
  if (node >= n) return;
  float4 pv = ((const float4*)p)[lane];
  float4 xv = ((const float4*)(x + (size_t)node * CH))[lane];
  float dot = xv.x * pv.x + xv.y * pv.y + xv.z * pv.z + xv.w * pv.w;
  float pn  = pv.x * pv.x + pv.y * pv.y + pv.z * pv.z + pv.w * pv.w;
  for (int off = 32; off; off >>= 1) {
    dot += __shfl_down(dot, off);
    pn  += __shfl_down(pn, off);
  }
  if (lane == 0) sc[node] = tanhf(dot / sqrtf(pn));
}

// full bitonic sort (descending score, ascending index tiebreak == jax.lax.top_k),
// single block, n in {2048, 4096}
__global__ __launch_bounds__(1024) void topk_sort(const float* __restrict__ sc, int n, int k,
                                                  int* __restrict__ perm, float* __restrict__ vals) {
  __shared__ float ss[4096];
  __shared__ int   si[4096];
  int tid = threadIdx.x;
  for (int i = tid; i < n; i += 1024) { ss[i] = sc[i]; si[i] = i; }
  __syncthreads();
  for (int size = 2; size <= n; size <<= 1) {
    for (int stride = size >> 1; stride > 0; stride >>= 1) {
      for (int i = tid; i < n; i += 1024) {
        int j = i ^ stride;
        if (j > i) {
          float a = ss[i], b = ss[j];
          int ia = si[i], ib = si[j];
          bool up = ((i & size) == 0);
          // pj: element j should precede element i in final (descending) order
          bool pj = (b > a) || (b == a && ib < ia);
          if (up ? pj : !pj) { ss[i] = b; ss[j] = a; si[i] = ib; si[j] = ia; }
        }
      }
      __syncthreads();
    }
  }
  for (int i = tid; i < k; i += 1024) { perm[i] = si[i]; vals[i] = ss[i]; }
}

// xo[i,:] = x[perm[i],:] * vals[i]
__global__ void pool_x(const float* __restrict__ x, const int* __restrict__ perm,
                       const float* __restrict__ vals, float* __restrict__ xo) {
  int i = blockIdx.x, c = threadIdx.x;
  xo[(size_t)i * CH + c] = x[(size_t)perm[i] * CH + c] * vals[i];
}

// Bc[t,j] = A[t, perm[j]]   (A diag already set to 1)
__global__ void gather_cols(const float* __restrict__ A, int n, const int* __restrict__ perm,
                            int k, float* __restrict__ Bc) {
  int j = blockIdx.x * blockDim.x + threadIdx.x;
  int t = blockIdx.y;
  if (j < k) Bc[(size_t)t * k + j] = A[(size_t)t * n + perm[j]];
}

// ---------------- tiled fp32 GEMM, 64x64 tile, 256 threads, 4x4/thread ----------------
// MODE 0: C[m,n] = dinv[m] * sum_k A[m,k]*B[k,n]                  (A row-major MxK)
// MODE 1: C[m,n] = relu(dinv[m] * sum_k A[k,m]*B[k,n] + bias[n])  (A is KxM physical, "A^T")
// MODE 2: C[m,n] = sum_k A[perm[m],k]*B[k,n]; diag (m==n) -> 0    (row-gathered A)
template <int MODE>
__global__ __launch_bounds__(256) void gemm64(const float* __restrict__ Am, int lda,
                                              const float* __restrict__ Bm, int ldb,
                                              float* __restrict__ Cm,
                                              int M, int N, int K,
                                              const float* __restrict__ dinv,
                                              const float* __restrict__ bias,
                                              const int* __restrict__ perm) {
  __shared__ float As[16][64];
  __shared__ float Bs[16][64];
  __shared__ int ps[64];
  const int tid = threadIdx.x;
  const int m0 = blockIdx.x * 64, n0 = blockIdx.y * 64;
  if (MODE == 2) { if (tid < 64) ps[tid] = perm[m0 + tid]; }
  float acc[4][4] = {{0.f}};
  const int tm = tid & 15, tn = tid >> 4;

  for (int kt = 0; kt < K; kt += 16) {
    __syncthreads();
    if (MODE == 1) {
#pragma unroll
      for (int r = 0; r < 4; ++r) {
        int idx = tid + r * 256;
        int kk = idx >> 6, mm = idx & 63;
        As[kk][mm] = Am[(size_t)(kt + kk) * lda + (m0 + mm)];
      }
    } else {
      int mm = tid >> 2, kq = (tid & 3) * 4;
      const float* src = (MODE == 2) ? (Am + (size_t)ps[mm] * lda + kt + kq)
                                     : (Am + (size_t)(m0 + mm) * lda + kt + kq);
      float4 v = *(const float4*)src;
      As[kq + 0][mm] = v.x; As[kq + 1][mm] = v.y; As[kq + 2][mm] = v.z; As[kq + 3][mm] = v.w;
    }
#pragma unroll
    for (int r = 0; r < 4; ++r) {
      int idx = tid + r * 256;
      int kk = idx >> 6, nn = idx & 63;
      Bs[kk][nn] = Bm[(size_t)(kt + kk) * ldb + (n0 + nn)];
    }
    __syncthreads();
#pragma unroll
    for (int kk = 0; kk < 16; ++kk) {
      float4 a = *(const float4*)&As[kk][tm * 4];
      float4 b = *(const float4*)&Bs[kk][tn * 4];
      acc[0][0] = fmaf(a.x, b.x, acc[0][0]);
      acc[0][1] = fmaf(a.x, b.y, acc[0][1]);
      acc[0][2] = fmaf(a.x, b.z, acc[0][2]);
      acc[0][3] = fmaf(a.x, b.w, acc[0][3]);
      acc[1][0] = fmaf(a.y, b.x, acc[1][0]);
      acc[1][1] = fmaf(a.y, b.y, acc[1][1]);
      acc[1][2] = fmaf(a.y, b.z, acc[1][2]);
      acc[1][3] = fmaf(a.y, b.w, acc[1][3]);
      acc[2][0] = fmaf(a.z, b.x, acc[2][0]);
      acc[2][1] = fmaf(a.z, b.y, acc[2][1]);
      acc[2][2] = fmaf(a.z, b.z, acc[2][2]);
      acc[2][3] = fmaf(a.z, b.w, acc[2][3]);
      acc[3][0] = fmaf(a.w, b.x, acc[3][0]);
      acc[3][1] = fmaf(a.w, b.y, acc[3][1]);
      acc[3][2] = fmaf(a.w, b.z, acc[3][2]);
      acc[3][3] = fmaf(a.w, b.w, acc[3][3]);
    }
  }

#pragma unroll
  for (int ii = 0; ii < 4; ++ii) {
    int m = m0 + tm * 4 + ii;
    int n = n0 + tn * 4;
    float v0 = acc[ii][0], v1 = acc[ii][1], v2 = acc[ii][2], v3 = acc[ii][3];
    if (MODE == 0) {
      float s = dinv[m];
      v0 *= s; v1 *= s; v2 *= s; v3 *= s;
    } else if (MODE == 1) {
      float s = dinv[m];
      v0 = fmaxf(fmaf(v0, s, bias[n + 0]), 0.f);
      v1 = fmaxf(fmaf(v1, s, bias[n + 1]), 0.f);
      v2 = fmaxf(fmaf(v2, s, bias[n + 2]), 0.f);
      v3 = fmaxf(fmaf(v3, s, bias[n + 3]), 0.f);
    } else {
      if (m == n + 0) v0 = 0.f;
      if (m == n + 1) v1 = 0.f;
      if (m == n + 2) v2 = 0.f;
      if (m == n + 3) v3 = 0.f;
    }
    *(float4*)&Cm[(size_t)m * N + n] = make_float4(v0, v1, v2, v3);
  }
}

// mean over rows -> normalize -> logits -> log_softmax; out[0:256]=emb, out[256:266]=logsm
__global__ __launch_bounds__(256) void finalize(const float* __restrict__ x2, int nr,
                                                const float* __restrict__ wc,
                                                const float* __restrict__ bc,
                                                float* __restrict__ out) {
  __shared__ float semb[256];
  __shared__ float red[256];
  __shared__ float slog[16];
  int c = threadIdx.x;
  float s = 0.f;
  for (int r = 0; r < nr; ++r) s += x2[(size_t)r * CH + c];
  float emb = s / (float)nr;
  red[c] = emb * emb;
  __syncthreads();
  for (int off = 128; off; off >>= 1) {
    if (c < off) red[c] += red[c + off];
    __syncthreads();
  }
  float denom = fmaxf(sqrtf(red[0]), 1e-12f);
  float en = emb / denom;
  semb[c] = en;
  out[c] = en;
  __syncthreads();
  if (c < 10) {
    float l = bc[c];
    for (int t = 0; t < CH; ++t) l = fmaf(semb[t], wc[c * CH + t], l);
    slog[c] = l;
  }
  __syncthreads();
  if (c == 0) {
    float mx = slog[0];
    for (int j = 1; j < 10; ++j) mx = fmaxf(mx, slog[j]);
    float se = 0.f;
    for (int j = 0; j < 10; ++j) se += expf(slog[j] - mx);
    float lse = mx + logf(se);
    for (int j = 0; j < 10; ++j) out[CH + j] = slog[j] - lse;
  }
}

// ---------------- orchestration ----------------

extern "C" void kernel_launch(void* const* d_in, const int* in_sizes, int n_in,
                              void* d_out, int out_size, void* d_ws, size_t ws_size,
                              hipStream_t stream) {
  const float* x  = (const float*)d_in[0];
  const int*   ei = (const int*)d_in[1];
  const float* w0 = (const float*)d_in[2];
  const float* b0 = (const float*)d_in[3];
  const float* w1 = (const float*)d_in[4];
  const float* b1 = (const float*)d_in[5];
  const float* w2 = (const float*)d_in[6];
  const float* b2 = (const float*)d_in[7];
  const float* p1 = (const float*)d_in[8];
  const float* p2 = (const float*)d_in[9];
  const float* wc = (const float*)d_in[10];
  const float* bc = (const float*)d_in[11];
  float* out = (float*)d_out;
  const int N0 = 4096, K1 = 2048, K2 = 1024;
  int E = in_sizes[1] / 2;

  float* W = (float*)d_ws;
  size_t off = 0;
  float* A   = W + off; off += (size_t)N0 * N0;   // 4096x4096
  float* Pa  = W + off; off += (size_t)K1 * K1;   // 2048x2048 pooled adj L1
  float* Pb  = W + off; off += (size_t)K2 * K2;   // 1024x1024 pooled adj L2
  float* Bc  = W + off; off += (size_t)N0 * K1;   // column-gather buffer (max 4096x2048)
  float* x0  = W + off; off += (size_t)N0 * CH;
  float* G   = W + off; off += (size_t)N0 * CH;   // dinv-scaled xW
  float* xp  = W + off; off += (size_t)K1 * CH;   // pooled/gated x
  float* x1  = W + off; off += (size_t)K1 * CH;
  float* x2  = W + off; off += (size_t)K2 * CH;
  float* sc  = W + off; off += 4096;
  float* vals = W + off; off += 4096;
  float* dinv = W + off; off += 4096;
  int* perm1 = (int*)(W + off); off += 4096;
  int* perm2 = (int*)(W + off); off += 4096;

  // ---- build adjacency ----
  fill_zero4<<<2048, 256, 0, stream>>>((float4*)A, (size_t)N0 * N0 / 4);
  scatter_edges<<<(E + 255) / 256, 256, 0, stream>>>(ei, E, N0, A);

  // ---- GCN 0 ----
  diag_fix<<<N0 / 256, 256, 0, stream>>>(A, N0);
  col_deg_dinv<<<N0 / 256, 256, 0, stream>>>(A, N0, dinv);
  gemm64<0><<<dim3(N0 / 64, CH / 64), 256, 0, stream>>>(x, CH, w0, CH, G, N0, CH, CH, dinv, nullptr, nullptr);
  gemm64<1><<<dim3(N0 / 64, CH / 64), 256, 0, stream>>>(A, N0, G, CH, x0, N0, CH, N0, dinv, b0, nullptr);

  // ---- pool 1 scores + top-k ----
  node_scores<<<N0 / 4, 256, 0, stream>>>(x0, p1, N0, sc);
  topk_sort<<<1, 1024, 0, stream>>>(sc, N0, K1, perm1, vals);

  // ---- augment (pooled submatrix only): Pa = B[perm1,:] @ B[:,perm1], B = A w/ diag 1 ----
  diag_set<<<N0 / 256, 256, 0, stream>>>(A, N0, 1.0f);
  gather_cols<<<dim3(K1 / 256, N0), 256, 0, stream>>>(A, N0, perm1, K1, Bc);
  gemm64<2><<<dim3(K1 / 64, K1 / 64), 256, 0, stream>>>(A, N0, Bc, K1, Pa, K1, K1, N0, nullptr, nullptr, perm1);
  pool_x<<<K1, 256, 0, stream>>>(x0, perm1, vals, xp);

  // ---- GCN 1 ----
  diag_fix<<<K1 / 256, 256, 0, stream>>>(Pa, K1);
  col_deg_dinv<<<K1 / 256, 256, 0, stream>>>(Pa, K1, dinv);
  gemm64<0><<<dim3(K1 / 64, CH / 64), 256, 0, stream>>>(xp, CH, w1, CH, G, K1, CH, CH, dinv, nullptr, nullptr);
  gemm64<1><<<dim3(K1 / 64, CH / 64), 256, 0, stream>>>(Pa, K1, G, CH, x1, K1, CH, K1, dinv, b1, nullptr);

  // ---- pool 2 scores + top-k ----
  node_scores<<<K1 / 4, 256, 0, stream>>>(x1, p2, K1, sc);
  topk_sort<<<1, 1024, 0, stream>>>(sc, K1, K2, perm2, vals);

  // ---- augment level 2 ----
  diag_set<<<K1 / 256, 256, 0, stream>>>(Pa, K1, 1.0f);
  gather_cols<<<dim3(K2 / 256, K1), 256, 0, stream>>>(Pa, K1, perm2, K2, Bc);
  gemm64<2><<<dim3(K2 / 64, K2 / 64), 256, 0, stream>>>(Pa, K1, Bc, K2, Pb, K2, K2, K1, nullptr, nullptr, perm2);
  pool_x<<<K2, 256, 0, stream>>>(x1, perm2, vals, xp);

  // ---- GCN 2 ----
  diag_fix<<<K2 / 256, 256, 0, stream>>>(Pb, K2);
  col_deg_dinv<<<K2 / 256, 256, 0, stream>>>(Pb, K2, dinv);
  gemm64<0><<<dim3(K2 / 64, CH / 64), 256, 0, stream>>>(xp, CH, w2, CH, G, K2, CH, CH, dinv, nullptr, nullptr);
  gemm64<1><<<dim3(K2 / 64, CH / 64), 256, 0, stream>>>(Pb, K2, G, CH, x2, K2, CH, K2, dinv, b2, nullptr);

  // ---- readout ----
  finalize<<<1, 256, 0, stream>>>(x2, K2, wc, bc, out);
}

// Round 2
// 1729.901 us; speedup vs baseline: 1.9441x; 1.9441x over previous
//
#include <hip/hip_runtime.h>
#include <math.h>

#define CH 256

// ---------------- utility kernels ----------------

__global__ void fill_zero4(float4* __restrict__ p, size_t n4) {
  size_t i = (size_t)blockIdx.x * blockDim.x + threadIdx.x;
  size_t st = (size_t)gridDim.x * blockDim.x;
  float4 z = make_float4(0.f, 0.f, 0.f, 0.f);
  for (; i < n4; i += st) p[i] = z;
}

__global__ void scatter_edges(const int* __restrict__ ei, int E, int n, float* __restrict__ A) {
  int e = blockIdx.x * blockDim.x + threadIdx.x;
  if (e < E) atomicAdd(&A[(size_t)ei[e] * n + ei[E + e]], 1.0f);
}

// where(diag != 0, diag, 2.0)
__global__ void diag_fix(float* __restrict__ A, int n) {
  int i = blockIdx.x * blockDim.x + threadIdx.x;
  if (i < n) { size_t id = (size_t)i * n + i; if (A[id] == 0.f) A[id] = 2.0f; }
}

__global__ void diag_set(float* __restrict__ A, int n, float v) {
  int i = blockIdx.x * blockDim.x + threadIdx.x;
  if (i < n) A[(size_t)i * n + i] = v;
}

// partial column sums: block (bx,by) sums rows [by*128, by*128+128) for cols bx*256+tx
// all values are small non-negative integers -> atomic fp32 adds are exact in any order
__global__ void col_deg_partial(const float* __restrict__ A, int n, float* __restrict__ deg) {
  int c = blockIdx.x * 256 + threadIdx.x;
  int j0 = blockIdx.y * 128;
  float s = 0.f;
#pragma unroll 4
  for (int j = 0; j < 128; ++j) s += A[(size_t)(j0 + j) * n + c];
  atomicAdd(&deg[c], s);
}

__global__ void deg_to_dinv(const float* __restrict__ deg, int n, float* __restrict__ dinv) {
  int i = blockIdx.x * blockDim.x + threadIdx.x;
  if (i < n) { float d = deg[i]; dinv[i] = (d > 0.f) ? 1.0f / sqrtf(d) : 0.f; }
}

// score[i] = tanh(dot(x[i,:], p) / ||p||), one wave per node
__global__ void node_scores(const float* __restrict__ x, const float* __restrict__ p,
                            int n, float* __restrict__ sc) {
  int wave = threadIdx.x >> 6;
  int lane = threadIdx.x & 63;
  int node = blockIdx.x * 4 + wave;
  if (node >= n) return;
  float4 pv = ((const float4*)p)[lane];
  float4 xv = ((const float4*)(x + (size_t)node * CH))[lane];
  float dot = xv.x * pv.x + xv.y * pv.y + xv.z * pv.z + xv.w * pv.w;
  float pn  = pv.x * pv.x + pv.y * pv.y + pv.z * pv.z + pv.w * pv.w;
  for (int off = 32; off; off >>= 1) {
    dot += __shfl_down(dot, off);
    pn  += __shfl_down(pn, off);
  }
  if (lane == 0) sc[node] = tanhf(dot / sqrtf(pn));
}

// full bitonic sort (descending score, ascending index tiebreak == jax.lax.top_k),
// single block, n in {2048, 4096}
__global__ __launch_bounds__(1024) void topk_sort(const float* __restrict__ sc, int n, int k,
                                                  int* __restrict__ perm, float* __restrict__ vals) {
  __shared__ float ss[4096];
  __shared__ int   si[4096];
  int tid = threadIdx.x;
  for (int i = tid; i < n; i += 1024) { ss[i] = sc[i]; si[i] = i; }
  __syncthreads();
  for (int size = 2; size <= n; size <<= 1) {
    for (int stride = size >> 1; stride > 0; stride >>= 1) {
      for (int i = tid; i < n; i += 1024) {
        int j = i ^ stride;
        if (j > i) {
          float a = ss[i], b = ss[j];
          int ia = si[i], ib = si[j];
          bool up = ((i & size) == 0);
          bool pj = (b > a) || (b == a && ib < ia);
          if (up ? pj : !pj) { ss[i] = b; ss[j] = a; si[i] = ib; si[j] = ia; }
        }
      }
      __syncthreads();
    }
  }
  for (int i = tid; i < k; i += 1024) { perm[i] = si[i]; vals[i] = ss[i]; }
}

// xo[i,:] = x[perm[i],:] * vals[i]
__global__ void pool_x(const float* __restrict__ x, const int* __restrict__ perm,
                       const float* __restrict__ vals, float* __restrict__ xo) {
  int i = blockIdx.x, c = threadIdx.x;
  xo[(size_t)i * CH + c] = x[(size_t)perm[i] * CH + c] * vals[i];
}

// Bc[t,j] = A[t, perm[j]]   (A diag already set to 1)
__global__ void gather_cols(const float* __restrict__ A, int n, const int* __restrict__ perm,
                            int k, float* __restrict__ Bc) {
  int j = blockIdx.x * blockDim.x + threadIdx.x;
  int t = blockIdx.y;
  if (j < k) Bc[(size_t)t * k + j] = A[(size_t)t * n + perm[j]];
}

// ---------------- tiled fp32 GEMM, 64x64 tile, 256 threads, 4x4/thread ----------------
// MODE 0: C[m,n] = dinv[m] * sum_k A[m,k]*B[k,n]                  (A row-major MxK)
// MODE 1: C[m,n] = relu(dinv[m] * sum_k A[k,m]*B[k,n] + bias[n])  (A is KxM physical, "A^T")
// MODE 2: C[m,n] = sum_k A[perm[m],k]*B[k,n]; diag (m==n) -> 0    (row-gathered A)
template <int MODE>
__global__ __launch_bounds__(256) void gemm64(const float* __restrict__ Am, int lda,
                                              const float* __restrict__ Bm, int ldb,
                                              float* __restrict__ Cm,
                                              int M, int N, int K,
                                              const float* __restrict__ dinv,
                                              const float* __restrict__ bias,
                                              const int* __restrict__ perm) {
  __shared__ float As[16][64];
  __shared__ float Bs[16][64];
  __shared__ int ps[64];
  const int tid = threadIdx.x;
  const int m0 = blockIdx.x * 64, n0 = blockIdx.y * 64;
  if (MODE == 2) { if (tid < 64) ps[tid] = perm[m0 + tid]; }
  float acc[4][4] = {{0.f}};
  const int tm = tid & 15, tn = tid >> 4;

  for (int kt = 0; kt < K; kt += 16) {
    __syncthreads();
    if (MODE == 1) {
#pragma unroll
      for (int r = 0; r < 4; ++r) {
        int idx = tid + r * 256;
        int kk = idx >> 6, mm = idx & 63;
        As[kk][mm] = Am[(size_t)(kt + kk) * lda + (m0 + mm)];
      }
    } else {
      int mm = tid >> 2, kq = (tid & 3) * 4;
      const float* src = (MODE == 2) ? (Am + (size_t)ps[mm] * lda + kt + kq)
                                     : (Am + (size_t)(m0 + mm) * lda + kt + kq);
      float4 v = *(const float4*)src;
      As[kq + 0][mm] = v.x; As[kq + 1][mm] = v.y; As[kq + 2][mm] = v.z; As[kq + 3][mm] = v.w;
    }
#pragma unroll
    for (int r = 0; r < 4; ++r) {
      int idx = tid + r * 256;
      int kk = idx >> 6, nn = idx & 63;
      Bs[kk][nn] = Bm[(size_t)(kt + kk) * ldb + (n0 + nn)];
    }
    __syncthreads();
#pragma unroll
    for (int kk = 0; kk < 16; ++kk) {
      float4 a = *(const float4*)&As[kk][tm * 4];
      float4 b = *(const float4*)&Bs[kk][tn * 4];
      acc[0][0] = fmaf(a.x, b.x, acc[0][0]);
      acc[0][1] = fmaf(a.x, b.y, acc[0][1]);
      acc[0][2] = fmaf(a.x, b.z, acc[0][2]);
      acc[0][3] = fmaf(a.x, b.w, acc[0][3]);
      acc[1][0] = fmaf(a.y, b.x, acc[1][0]);
      acc[1][1] = fmaf(a.y, b.y, acc[1][1]);
      acc[1][2] = fmaf(a.y, b.z, acc[1][2]);
      acc[1][3] = fmaf(a.y, b.w, acc[1][3]);
      acc[2][0] = fmaf(a.z, b.x, acc[2][0]);
      acc[2][1] = fmaf(a.z, b.y, acc[2][1]);
      acc[2][2] = fmaf(a.z, b.z, acc[2][2]);
      acc[2][3] = fmaf(a.z, b.w, acc[2][3]);
      acc[3][0] = fmaf(a.w, b.x, acc[3][0]);
      acc[3][1] = fmaf(a.w, b.y, acc[3][1]);
      acc[3][2] = fmaf(a.w, b.z, acc[3][2]);
      acc[3][3] = fmaf(a.w, b.w, acc[3][3]);
    }
  }

#pragma unroll
  for (int ii = 0; ii < 4; ++ii) {
    int m = m0 + tm * 4 + ii;
    int n = n0 + tn * 4;
    float v0 = acc[ii][0], v1 = acc[ii][1], v2 = acc[ii][2], v3 = acc[ii][3];
    if (MODE == 0) {
      float s = dinv[m];
      v0 *= s; v1 *= s; v2 *= s; v3 *= s;
    } else if (MODE == 1) {
      float s = dinv[m];
      v0 = fmaxf(fmaf(v0, s, bias[n + 0]), 0.f);
      v1 = fmaxf(fmaf(v1, s, bias[n + 1]), 0.f);
      v2 = fmaxf(fmaf(v2, s, bias[n + 2]), 0.f);
      v3 = fmaxf(fmaf(v3, s, bias[n + 3]), 0.f);
    } else {
      if (m == n + 0) v0 = 0.f;
      if (m == n + 1) v1 = 0.f;
      if (m == n + 2) v2 = 0.f;
      if (m == n + 3) v3 = 0.f;
    }
    *(float4*)&Cm[(size_t)m * N + n] = make_float4(v0, v1, v2, v3);
  }
}

// mean over rows -> normalize -> logits -> log_softmax; out[0:256]=emb, out[256:266]=logsm
__global__ __launch_bounds__(256) void finalize(const float* __restrict__ x2, int nr,
                                                const float* __restrict__ wc,
                                                const float* __restrict__ bc,
                                                float* __restrict__ out) {
  __shared__ float semb[256];
  __shared__ float red[256];
  __shared__ float slog[16];
  int c = threadIdx.x;
  float s = 0.f;
  for (int r = 0; r < nr; ++r) s += x2[(size_t)r * CH + c];
  float emb = s / (float)nr;
  red[c] = emb * emb;
  __syncthreads();
  for (int off = 128; off; off >>= 1) {
    if (c < off) red[c] += red[c + off];
    __syncthreads();
  }
  float denom = fmaxf(sqrtf(red[0]), 1e-12f);
  float en = emb / denom;
  semb[c] = en;
  out[c] = en;
  __syncthreads();
  if (c < 10) {
    float l = bc[c];
    for (int t = 0; t < CH; ++t) l = fmaf(semb[t], wc[c * CH + t], l);
    slog[c] = l;
  }
  __syncthreads();
  if (c == 0) {
    float mx = slog[0];
    for (int j = 1; j < 10; ++j) mx = fmaxf(mx, slog[j]);
    float se = 0.f;
    for (int j = 0; j < 10; ++j) se += expf(slog[j] - mx);
    float lse = mx + logf(se);
    for (int j = 0; j < 10; ++j) out[CH + j] = slog[j] - lse;
  }
}

// ---------------- orchestration ----------------

extern "C" void kernel_launch(void* const* d_in, const int* in_sizes, int n_in,
                              void* d_out, int out_size, void* d_ws, size_t ws_size,
                              hipStream_t stream) {
  const float* x  = (const float*)d_in[0];
  const int*   ei = (const int*)d_in[1];
  const float* w0 = (const float*)d_in[2];
  const float* b0 = (const float*)d_in[3];
  const float* w1 = (const float*)d_in[4];
  const float* b1 = (const float*)d_in[5];
  const float* w2 = (const float*)d_in[6];
  const float* b2 = (const float*)d_in[7];
  const float* p1 = (const float*)d_in[8];
  const float* p2 = (const float*)d_in[9];
  const float* wc = (const float*)d_in[10];
  const float* bc = (const float*)d_in[11];
  float* out = (float*)d_out;
  const int N0 = 4096, K1 = 2048, K2 = 1024;
  int E = in_sizes[1] / 2;

  float* W = (float*)d_ws;
  size_t off = 0;
  float* A   = W + off; off += (size_t)N0 * N0;   // 4096x4096
  float* Pa  = W + off; off += (size_t)K1 * K1;   // 2048x2048 pooled adj L1
  float* Pb  = W + off; off += (size_t)K2 * K2;   // 1024x1024 pooled adj L2
  float* Bc  = W + off; off += (size_t)N0 * K1;   // column-gather buffer (max 4096x2048)
  float* x0  = W + off; off += (size_t)N0 * CH;
  float* G   = W + off; off += (size_t)N0 * CH;   // dinv-scaled xW
  float* xp  = W + off; off += (size_t)K1 * CH;   // pooled/gated x
  float* x1  = W + off; off += (size_t)K1 * CH;
  float* x2  = W + off; off += (size_t)K2 * CH;
  float* sc  = W + off; off += 4096;
  float* vals = W + off; off += 4096;
  float* deg  = W + off; off += 4096;
  float* dinv = W + off; off += 4096;
  int* perm1 = (int*)(W + off); off += 4096;
  int* perm2 = (int*)(W + off); off += 4096;

  // ---- build adjacency ----
  fill_zero4<<<2048, 256, 0, stream>>>((float4*)A, (size_t)N0 * N0 / 4);
  scatter_edges<<<(E + 255) / 256, 256, 0, stream>>>(ei, E, N0, A);

  // ---- GCN 0 ----
  diag_fix<<<N0 / 256, 256, 0, stream>>>(A, N0);
  fill_zero4<<<4, 256, 0, stream>>>((float4*)deg, N0 / 4);
  col_deg_partial<<<dim3(N0 / 256, N0 / 128), 256, 0, stream>>>(A, N0, deg);
  deg_to_dinv<<<N0 / 256, 256, 0, stream>>>(deg, N0, dinv);
  gemm64<0><<<dim3(N0 / 64, CH / 64), 256, 0, stream>>>(x, CH, w0, CH, G, N0, CH, CH, dinv, nullptr, nullptr);
  gemm64<1><<<dim3(N0 / 64, CH / 64), 256, 0, stream>>>(A, N0, G, CH, x0, N0, CH, N0, dinv, b0, nullptr);

  // ---- pool 1 scores + top-k ----
  node_scores<<<N0 / 4, 256, 0, stream>>>(x0, p1, N0, sc);
  topk_sort<<<1, 1024, 0, stream>>>(sc, N0, K1, perm1, vals);

  // ---- augment (pooled submatrix only): Pa = B[perm1,:] @ B[:,perm1], B = A w/ diag 1 ----
  diag_set<<<N0 / 256, 256, 0, stream>>>(A, N0, 1.0f);
  gather_cols<<<dim3(K1 / 256, N0), 256, 0, stream>>>(A, N0, perm1, K1, Bc);
  gemm64<2><<<dim3(K1 / 64, K1 / 64), 256, 0, stream>>>(A, N0, Bc, K1, Pa, K1, K1, N0, nullptr, nullptr, perm1);
  pool_x<<<K1, 256, 0, stream>>>(x0, perm1, vals, xp);

  // ---- GCN 1 ----
  diag_fix<<<K1 / 256, 256, 0, stream>>>(Pa, K1);
  fill_zero4<<<1, 256, 0, stream>>>((float4*)deg, K1 / 4);
  col_deg_partial<<<dim3(K1 / 256, K1 / 128), 256, 0, stream>>>(Pa, K1, deg);
  deg_to_dinv<<<K1 / 256, 256, 0, stream>>>(deg, K1, dinv);
  gemm64<0><<<dim3(K1 / 64, CH / 64), 256, 0, stream>>>(xp, CH, w1, CH, G, K1, CH, CH, dinv, nullptr, nullptr);
  gemm64<1><<<dim3(K1 / 64, CH / 64), 256, 0, stream>>>(Pa, K1, G, CH, x1, K1, CH, K1, dinv, b1, nullptr);

  // ---- pool 2 scores + top-k ----
  node_scores<<<K1 / 4, 256, 0, stream>>>(x1, p2, K1, sc);
  topk_sort<<<1, 1024, 0, stream>>>(sc, K1, K2, perm2, vals);

  // ---- augment level 2 ----
  diag_set<<<K1 / 256, 256, 0, stream>>>(Pa, K1, 1.0f);
  gather_cols<<<dim3(K2 / 256, K1), 256, 0, stream>>>(Pa, K1, perm2, K2, Bc);
  gemm64<2><<<dim3(K2 / 64, K2 / 64), 256, 0, stream>>>(Pa, K1, Bc, K2, Pb, K2, K2, K1, nullptr, nullptr, perm2);
  pool_x<<<K2, 256, 0, stream>>>(x1, perm2, vals, xp);

  // ---- GCN 2 ----
  diag_fix<<<K2 / 256, 256, 0, stream>>>(Pb, K2);
  fill_zero4<<<1, 256, 0, stream>>>((float4*)deg, K2 / 4);
  col_deg_partial<<<dim3(K2 / 256, K2 / 128), 256, 0, stream>>>(Pb, K2, deg);
  deg_to_dinv<<<K2 / 256, 256, 0, stream>>>(deg, K2, dinv);
  gemm64<0><<<dim3(K2 / 64, CH / 64), 256, 0, stream>>>(xp, CH, w2, CH, G, K2, CH, CH, dinv, nullptr, nullptr);
  gemm64<1><<<dim3(K2 / 64, CH / 64), 256, 0, stream>>>(Pb, K2, G, CH, x2, K2, CH, K2, dinv, b2, nullptr);

  // ---- readout ----
  finalize<<<1, 256, 0, stream>>>(x2, K2, wc, bc, out);
}

// Round 3
// 1243.383 us; speedup vs baseline: 2.7048x; 1.3913x over previous
//
#include <hip/hip_runtime.h>
#include <math.h>

#define CH 256

typedef short short8 __attribute__((ext_vector_type(8)));
typedef float f32x4 __attribute__((ext_vector_type(4)));

// f32 -> bf16 bits (RNE); all adjacency values are small ints, exact either way
__device__ inline ushort f2bf(float f) {
  unsigned u = __float_as_uint(f);
  unsigned r = (u + 0x7FFFu + ((u >> 16) & 1u)) >> 16;
  return (ushort)r;
}

// ---------------- utility kernels ----------------

__global__ void fill_zero4(float4* __restrict__ p, size_t n4) {
  size_t i = (size_t)blockIdx.x * blockDim.x + threadIdx.x;
  size_t st = (size_t)gridDim.x * blockDim.x;
  float4 z = make_float4(0.f, 0.f, 0.f, 0.f);
  for (; i < n4; i += st) p[i] = z;
}

__global__ void scatter_edges(const int* __restrict__ ei, int E, int n, float* __restrict__ A) {
  int e = blockIdx.x * blockDim.x + threadIdx.x;
  if (e < E) atomicAdd(&A[(size_t)ei[e] * n + ei[E + e]], 1.0f);
}

// where(diag != 0, diag, 2.0)
__global__ void diag_fix(float* __restrict__ A, int n) {
  int i = blockIdx.x * blockDim.x + threadIdx.x;
  if (i < n) { size_t id = (size_t)i * n + i; if (A[id] == 0.f) A[id] = 2.0f; }
}

__global__ void diag_set(float* __restrict__ A, int n, float v) {
  int i = blockIdx.x * blockDim.x + threadIdx.x;
  if (i < n) A[(size_t)i * n + i] = v;
}

__global__ void fill_i32(int* __restrict__ p, int n, int v) {
  int i = blockIdx.x * blockDim.x + threadIdx.x;
  if (i < n) p[i] = v;
}

__global__ void scatter_rank(const int* __restrict__ perm, int k, int* __restrict__ rank) {
  int j = blockIdx.x * blockDim.x + threadIdx.x;
  if (j < k) rank[perm[j]] = j;
}

// partial column sums (exact: small non-negative ints)
__global__ void col_deg_partial(const float* __restrict__ A, int n, float* __restrict__ deg) {
  int c = blockIdx.x * 256 + threadIdx.x;
  int j0 = blockIdx.y * 128;
  float s = 0.f;
#pragma unroll 4
  for (int j = 0; j < 128; ++j) s += A[(size_t)(j0 + j) * n + c];
  atomicAdd(&deg[c], s);
}

__global__ void deg_to_dinv(const float* __restrict__ deg, int n, float* __restrict__ dinv) {
  int i = blockIdx.x * blockDim.x + threadIdx.x;
  if (i < n) { float d = deg[i]; dinv[i] = (d > 0.f) ? 1.0f / sqrtf(d) : 0.f; }
}

// score[i] = tanh(dot(x[i,:], p) / ||p||), one wave per node
__global__ void node_scores(const float* __restrict__ x, const float* __restrict__ p,
                            int n, float* __restrict__ sc) {
  int wave = threadIdx.x >> 6;
  int lane = threadIdx.x & 63;
  int node = blockIdx.x * 4 + wave;
  if (node >= n) return;
  float4 pv = ((const float4*)p)[lane];
  float4 xv = ((const float4*)(x + (size_t)node * CH))[lane];
  float dot = xv.x * pv.x + xv.y * pv.y + xv.z * pv.z + xv.w * pv.w;
  float pn  = pv.x * pv.x + pv.y * pv.y + pv.z * pv.z + pv.w * pv.w;
  for (int off = 32; off; off >>= 1) {
    dot += __shfl_down(dot, off);
    pn  += __shfl_down(pn, off);
  }
  if (lane == 0) sc[node] = tanhf(dot / sqrtf(pn));
}

// bitonic sort (desc score, asc index tiebreak == jax.lax.top_k), n in {2048,4096}
__global__ __launch_bounds__(1024) void topk_sort(const float* __restrict__ sc, int n, int k,
                                                  int* __restrict__ perm, float* __restrict__ vals) {
  __shared__ float ss[4096];
  __shared__ int   si[4096];
  int tid = threadIdx.x;
  for (int i = tid; i < n; i += 1024) { ss[i] = sc[i]; si[i] = i; }
  __syncthreads();
  for (int size = 2; size <= n; size <<= 1) {
    for (int stride = size >> 1; stride > 0; stride >>= 1) {
      for (int i = tid; i < n; i += 1024) {
        int j = i ^ stride;
        if (j > i) {
          float a = ss[i], b = ss[j];
          int ia = si[i], ib = si[j];
          bool up = ((i & size) == 0);
          bool pj = (b > a) || (b == a && ib < ia);
          if (up ? pj : !pj) { ss[i] = b; ss[j] = a; si[i] = ib; si[j] = ia; }
        }
      }
      __syncthreads();
    }
  }
  for (int i = tid; i < k; i += 1024) { perm[i] = si[i]; vals[i] = ss[i]; }
}

// xo[i,:] = x[perm[i],:] * vals[i]
__global__ void pool_x(const float* __restrict__ x, const int* __restrict__ perm,
                       const float* __restrict__ vals, float* __restrict__ xo) {
  int i = blockIdx.x, c = threadIdx.x;
  xo[(size_t)i * CH + c] = x[(size_t)perm[i] * CH + c] * vals[i];
}

// ---------------- augment operand prep (bf16, exact for small ints) ----------------

// O[m][0:n] = bf16(A[perm[m]][0:n]) — coalesced row gather + convert
__global__ void rowgather_cvt(const float* __restrict__ A, const int* __restrict__ perm,
                              int n, ushort* __restrict__ O) {
  int m = blockIdx.y;
  int k4 = (blockIdx.x * 256 + threadIdx.x) * 4;
  float4 v = *(const float4*)&A[(size_t)perm[m] * n + k4];
  ushort4 o;
  o.x = f2bf(v.x); o.y = f2bf(v.y); o.z = f2bf(v.z); o.w = f2bf(v.w);
  *(ushort4*)&O[(size_t)m * n + k4] = o;
}

// For cols j with rank[j]>=0: O[rank[j]][0:n] = bf16(A[0:n][j]).
// LDS-tiled: reads and writes both coalesced.
__global__ __launch_bounds__(256) void transpose_gather_cvt(
    const float* __restrict__ In, const int* __restrict__ rank,
    int n, ushort* __restrict__ O) {
  __shared__ float t[64][65];
  __shared__ int rk[64];
  int j0 = blockIdx.x * 64, i0 = blockIdx.y * 64;
  int tx = threadIdx.x & 63, ty4 = threadIdx.x >> 6;
#pragma unroll
  for (int r = 0; r < 64; r += 4)
    t[ty4 + r][tx] = In[(size_t)(i0 + ty4 + r) * n + j0 + tx];
  if (threadIdx.x < 64) rk[threadIdx.x] = rank[j0 + threadIdx.x];
  __syncthreads();
#pragma unroll
  for (int r = 0; r < 64; r += 4) {
    int c = ty4 + r;
    int rr = rk[c];
    if (rr >= 0) O[(size_t)rr * n + i0 + tx] = f2bf(t[tx][c]);
  }
}

// ---------------- bf16 MFMA augment GEMM: C[m][n] = sum_k Arow[m][k]*Brow[n][k] ----------------
// 128x128 tile, BK=64, 4 waves (2x2 of 64x64), 16x16x32 bf16 MFMA. diag(m==n) -> 0. fp32 out.
__global__ __launch_bounds__(256) void mfma_augment(const ushort* __restrict__ Arow,
                                                    const ushort* __restrict__ Brow,
                                                    float* __restrict__ C, int Msz, int K) {
  __shared__ ushort As[128][72];  // +8 pad: row stride 144B (16B-aligned, conflict-free-ish)
  __shared__ ushort Bs[128][72];
  const int tid = threadIdx.x;
  const int wave = tid >> 6, lane = tid & 63;
  const int wm = (wave & 1) * 64, wn = (wave >> 1) * 64;
  const int m0 = blockIdx.x * 128, n0 = blockIdx.y * 128;
  const int lrow = lane & 15;
  const int kq = (lane >> 4) * 8;
  f32x4 acc[4][4] = {};

  for (int kt = 0; kt < K; kt += 64) {
    __syncthreads();
#pragma unroll
    for (int r = 0; r < 4; ++r) {
      int c = tid + r * 256;            // 1024 chunks of 8 bf16
      int row = c >> 3, ks = (c & 7) * 8;
      *(uint4*)&As[row][ks] = *(const uint4*)&Arow[(size_t)(m0 + row) * K + kt + ks];
      *(uint4*)&Bs[row][ks] = *(const uint4*)&Brow[(size_t)(n0 + row) * K + kt + ks];
    }
    __syncthreads();
#pragma unroll
    for (int ks = 0; ks < 2; ++ks) {
      short8 af[4], bf[4];
#pragma unroll
      for (int t = 0; t < 4; ++t) {
        af[t] = *(const short8*)&As[wm + t * 16 + lrow][ks * 32 + kq];
        bf[t] = *(const short8*)&Bs[wn + t * 16 + lrow][ks * 32 + kq];
      }
#pragma unroll
      for (int mt = 0; mt < 4; ++mt)
#pragma unroll
        for (int nt = 0; nt < 4; ++nt)
          acc[mt][nt] = __builtin_amdgcn_mfma_f32_16x16x32_bf16(af[mt], bf[nt], acc[mt][nt], 0, 0, 0);
    }
  }

  // C/D layout: col = lane&15, row = (lane>>4)*4 + reg
  const int crow = (lane >> 4) * 4, ccol = lane & 15;
#pragma unroll
  for (int mt = 0; mt < 4; ++mt)
#pragma unroll
    for (int nt = 0; nt < 4; ++nt) {
      int gm = m0 + wm + mt * 16 + crow;
      int gn = n0 + wn + nt * 16 + ccol;
#pragma unroll
      for (int r = 0; r < 4; ++r) {
        float v = acc[mt][nt][r];
        C[(size_t)(gm + r) * Msz + gn] = (gm + r == gn) ? 0.f : v;
      }
    }
}

// ---------------- tiled fp32 GEMM, 64x64 tile (GCN layers) ----------------
// MODE 0: C[m,n] = dinv[m] * sum_k A[m,k]*B[k,n]
// MODE 1: C[m,n] = relu(dinv[m] * sum_k A[k,m]*B[k,n] + bias[n])
template <int MODE>
__global__ __launch_bounds__(256) void gemm64(const float* __restrict__ Am, int lda,
                                              const float* __restrict__ Bm, int ldb,
                                              float* __restrict__ Cm,
                                              int M, int N, int K,
                                              const float* __restrict__ dinv,
                                              const float* __restrict__ bias) {
  __shared__ float As[16][64];
  __shared__ float Bs[16][64];
  const int tid = threadIdx.x;
  const int m0 = blockIdx.x * 64, n0 = blockIdx.y * 64;
  float acc[4][4] = {{0.f}};
  const int tm = tid & 15, tn = tid >> 4;

  for (int kt = 0; kt < K; kt += 16) {
    __syncthreads();
    if (MODE == 1) {
#pragma unroll
      for (int r = 0; r < 4; ++r) {
        int idx = tid + r * 256;
        int kk = idx >> 6, mm = idx & 63;
        As[kk][mm] = Am[(size_t)(kt + kk) * lda + (m0 + mm)];
      }
    } else {
      int mm = tid >> 2, kq = (tid & 3) * 4;
      float4 v = *(const float4*)(Am + (size_t)(m0 + mm) * lda + kt + kq);
      As[kq + 0][mm] = v.x; As[kq + 1][mm] = v.y; As[kq + 2][mm] = v.z; As[kq + 3][mm] = v.w;
    }
#pragma unroll
    for (int r = 0; r < 4; ++r) {
      int idx = tid + r * 256;
      int kk = idx >> 6, nn = idx & 63;
      Bs[kk][nn] = Bm[(size_t)(kt + kk) * ldb + (n0 + nn)];
    }
    __syncthreads();
#pragma unroll
    for (int kk = 0; kk < 16; ++kk) {
      float4 a = *(const float4*)&As[kk][tm * 4];
      float4 b = *(const float4*)&Bs[kk][tn * 4];
      acc[0][0] = fmaf(a.x, b.x, acc[0][0]);
      acc[0][1] = fmaf(a.x, b.y, acc[0][1]);
      acc[0][2] = fmaf(a.x, b.z, acc[0][2]);
      acc[0][3] = fmaf(a.x, b.w, acc[0][3]);
      acc[1][0] = fmaf(a.y, b.x, acc[1][0]);
      acc[1][1] = fmaf(a.y, b.y, acc[1][1]);
      acc[1][2] = fmaf(a.y, b.z, acc[1][2]);
      acc[1][3] = fmaf(a.y, b.w, acc[1][3]);
      acc[2][0] = fmaf(a.z, b.x, acc[2][0]);
      acc[2][1] = fmaf(a.z, b.y, acc[2][1]);
      acc[2][2] = fmaf(a.z, b.z, acc[2][2]);
      acc[2][3] = fmaf(a.z, b.w, acc[2][3]);
      acc[3][0] = fmaf(a.w, b.x, acc[3][0]);
      acc[3][1] = fmaf(a.w, b.y, acc[3][1]);
      acc[3][2] = fmaf(a.w, b.z, acc[3][2]);
      acc[3][3] = fmaf(a.w, b.w, acc[3][3]);
    }
  }

#pragma unroll
  for (int ii = 0; ii < 4; ++ii) {
    int m = m0 + tm * 4 + ii;
    int n = n0 + tn * 4;
    float v0 = acc[ii][0], v1 = acc[ii][1], v2 = acc[ii][2], v3 = acc[ii][3];
    if (MODE == 0) {
      float s = dinv[m];
      v0 *= s; v1 *= s; v2 *= s; v3 *= s;
    } else {
      float s = dinv[m];
      v0 = fmaxf(fmaf(v0, s, bias[n + 0]), 0.f);
      v1 = fmaxf(fmaf(v1, s, bias[n + 1]), 0.f);
      v2 = fmaxf(fmaf(v2, s, bias[n + 2]), 0.f);
      v3 = fmaxf(fmaf(v3, s, bias[n + 3]), 0.f);
    }
    *(float4*)&Cm[(size_t)m * N + n] = make_float4(v0, v1, v2, v3);
  }
}

// mean over rows -> normalize -> logits -> log_softmax
__global__ __launch_bounds__(256) void finalize(const float* __restrict__ x2, int nr,
                                                const float* __restrict__ wc,
                                                const float* __restrict__ bc,
                                                float* __restrict__ out) {
  __shared__ float semb[256];
  __shared__ float red[256];
  __shared__ float slog[16];
  int c = threadIdx.x;
  float s = 0.f;
  for (int r = 0; r < nr; ++r) s += x2[(size_t)r * CH + c];
  float emb = s / (float)nr;
  red[c] = emb * emb;
  __syncthreads();
  for (int off = 128; off; off >>= 1) {
    if (c < off) red[c] += red[c + off];
    __syncthreads();
  }
  float denom = fmaxf(sqrtf(red[0]), 1e-12f);
  float en = emb / denom;
  semb[c] = en;
  out[c] = en;
  __syncthreads();
  if (c < 10) {
    float l = bc[c];
    for (int t = 0; t < CH; ++t) l = fmaf(semb[t], wc[c * CH + t], l);
    slog[c] = l;
  }
  __syncthreads();
  if (c == 0) {
    float mx = slog[0];
    for (int j = 1; j < 10; ++j) mx = fmaxf(mx, slog[j]);
    float se = 0.f;
    for (int j = 0; j < 10; ++j) se += expf(slog[j] - mx);
    float lse = mx + logf(se);
    for (int j = 0; j < 10; ++j) out[CH + j] = slog[j] - lse;
  }
}

// ---------------- orchestration ----------------

extern "C" void kernel_launch(void* const* d_in, const int* in_sizes, int n_in,
                              void* d_out, int out_size, void* d_ws, size_t ws_size,
                              hipStream_t stream) {
  const float* x  = (const float*)d_in[0];
  const int*   ei = (const int*)d_in[1];
  const float* w0 = (const float*)d_in[2];
  const float* b0 = (const float*)d_in[3];
  const float* w1 = (const float*)d_in[4];
  const float* b1 = (const float*)d_in[5];
  const float* w2 = (const float*)d_in[6];
  const float* b2 = (const float*)d_in[7];
  const float* p1 = (const float*)d_in[8];
  const float* p2 = (const float*)d_in[9];
  const float* wc = (const float*)d_in[10];
  const float* bc = (const float*)d_in[11];
  float* out = (float*)d_out;
  const int N0 = 4096, K1 = 2048, K2 = 1024;
  int E = in_sizes[1] / 2;

  float* W = (float*)d_ws;
  size_t off = 0;
  float* A    = W + off; off += (size_t)N0 * N0;       // 4096x4096 fp32
  float* Pa   = W + off; off += (size_t)K1 * K1;       // 2048x2048 fp32
  float* Pb   = W + off; off += (size_t)K2 * K2;       // 1024x1024 fp32
  ushort* Arow = (ushort*)(W + off); off += (size_t)K1 * N0 / 2;  // bf16 2048x4096
  ushort* Brow = (ushort*)(W + off); off += (size_t)K1 * N0 / 2;  // bf16 2048x4096
  float* x0  = W + off; off += (size_t)N0 * CH;
  float* G   = W + off; off += (size_t)N0 * CH;
  float* xp  = W + off; off += (size_t)K1 * CH;
  float* x1  = W + off; off += (size_t)K1 * CH;
  float* x2  = W + off; off += (size_t)K2 * CH;
  float* sc  = W + off; off += 4096;                   // scores; reused as rank[] after top-k
  float* vals = W + off; off += 4096;
  float* deg  = W + off; off += 4096;
  float* dinv = W + off; off += 4096;
  int* perm1 = (int*)(W + off); off += 4096;
  int* perm2 = (int*)(W + off); off += 4096;
  int* rank = (int*)sc;  // sc dead after topk_sort; reused per level

  // ---- build adjacency ----
  fill_zero4<<<2048, 256, 0, stream>>>((float4*)A, (size_t)N0 * N0 / 4);
  scatter_edges<<<(E + 255) / 256, 256, 0, stream>>>(ei, E, N0, A);

  // ---- GCN 0 ----
  diag_fix<<<N0 / 256, 256, 0, stream>>>(A, N0);
  fill_zero4<<<4, 256, 0, stream>>>((float4*)deg, N0 / 4);
  col_deg_partial<<<dim3(N0 / 256, N0 / 128), 256, 0, stream>>>(A, N0, deg);
  deg_to_dinv<<<N0 / 256, 256, 0, stream>>>(deg, N0, dinv);
  gemm64<0><<<dim3(N0 / 64, CH / 64), 256, 0, stream>>>(x, CH, w0, CH, G, N0, CH, CH, dinv, nullptr);
  gemm64<1><<<dim3(N0 / 64, CH / 64), 256, 0, stream>>>(A, N0, G, CH, x0, N0, CH, N0, dinv, b0);

  // ---- pool 1 scores + top-k ----
  node_scores<<<N0 / 4, 256, 0, stream>>>(x0, p1, N0, sc);
  topk_sort<<<1, 1024, 0, stream>>>(sc, N0, K1, perm1, vals);

  // ---- augment L1 (bf16 MFMA, exact): Pa = (B@B)[perm1][:,perm1], B = A w/ diag 1 ----
  diag_set<<<N0 / 256, 256, 0, stream>>>(A, N0, 1.0f);
  fill_i32<<<N0 / 256, 256, 0, stream>>>(rank, N0, -1);
  scatter_rank<<<K1 / 256, 256, 0, stream>>>(perm1, K1, rank);
  rowgather_cvt<<<dim3(N0 / 1024, K1), 256, 0, stream>>>(A, perm1, N0, Arow);
  transpose_gather_cvt<<<dim3(N0 / 64, N0 / 64), 256, 0, stream>>>(A, rank, N0, Brow);
  mfma_augment<<<dim3(K1 / 128, K1 / 128), 256, 0, stream>>>(Arow, Brow, Pa, K1, N0);
  pool_x<<<K1, 256, 0, stream>>>(x0, perm1, vals, xp);

  // ---- GCN 1 ----
  diag_fix<<<K1 / 256, 256, 0, stream>>>(Pa, K1);
  fill_zero4<<<1, 256, 0, stream>>>((float4*)deg, K1 / 4);
  col_deg_partial<<<dim3(K1 / 256, K1 / 128), 256, 0, stream>>>(Pa, K1, deg);
  deg_to_dinv<<<K1 / 256, 256, 0, stream>>>(deg, K1, dinv);
  gemm64<0><<<dim3(K1 / 64, CH / 64), 256, 0, stream>>>(xp, CH, w1, CH, G, K1, CH, CH, dinv, nullptr);
  gemm64<1><<<dim3(K1 / 64, CH / 64), 256, 0, stream>>>(Pa, K1, G, CH, x1, K1, CH, K1, dinv, b1);

  // ---- pool 2 scores + top-k ----
  node_scores<<<K1 / 4, 256, 0, stream>>>(x1, p2, K1, sc);
  topk_sort<<<1, 1024, 0, stream>>>(sc, K1, K2, perm2, vals);

  // ---- augment L2 ----
  diag_set<<<K1 / 256, 256, 0, stream>>>(Pa, K1, 1.0f);
  fill_i32<<<K1 / 256, 256, 0, stream>>>(rank, K1, -1);
  scatter_rank<<<K2 / 256, 256, 0, stream>>>(perm2, K2, rank);
  rowgather_cvt<<<dim3(K1 / 1024, K2), 256, 0, stream>>>(Pa, perm2, K1, Arow);
  transpose_gather_cvt<<<dim3(K1 / 64, K1 / 64), 256, 0, stream>>>(Pa, rank, K1, Brow);
  mfma_augment<<<dim3(K2 / 128, K2 / 128), 256, 0, stream>>>(Arow, Brow, Pb, K2, K1);
  pool_x<<<K2, 256, 0, stream>>>(x1, perm2, vals, xp);

  // ---- GCN 2 ----
  diag_fix<<<K2 / 256, 256, 0, stream>>>(Pb, K2);
  fill_zero4<<<1, 256, 0, stream>>>((float4*)deg, K2 / 4);
  col_deg_partial<<<dim3(K2 / 256, K2 / 128), 256, 0, stream>>>(Pb, K2, deg);
  deg_to_dinv<<<K2 / 256, 256, 0, stream>>>(deg, K2, dinv);
  gemm64<0><<<dim3(K2 / 64, CH / 64), 256, 0, stream>>>(xp, CH, w2, CH, G, K2, CH, CH, dinv, nullptr);
  gemm64<1><<<dim3(K2 / 64, CH / 64), 256, 0, stream>>>(Pb, K2, G, CH, x2, K2, CH, K2, dinv, b2);

  // ---- readout ----
  finalize<<<1, 256, 0, stream>>>(x2, K2, wc, bc, out);
}

// Round 4
// 799.941 us; speedup vs baseline: 4.2042x; 1.5543x over previous
//
#include <hip/hip_runtime.h>
#include <math.h>

#define CH 256

typedef short short8 __attribute__((ext_vector_type(8)));
typedef float f32x4 __attribute__((ext_vector_type(4)));

// f32 -> bf16 bits (RNE); adjacency values are small ints, exact
__device__ inline ushort f2bf(float f) {
  unsigned u = __float_as_uint(f);
  unsigned r = (u + 0x7FFFu + ((u >> 16) & 1u)) >> 16;
  return (ushort)r;
}

// ---------------- utility kernels ----------------

__global__ void fill_zero4(float4* __restrict__ p, size_t n4) {
  size_t i = (size_t)blockIdx.x * blockDim.x + threadIdx.x;
  size_t st = (size_t)gridDim.x * blockDim.x;
  float4 z = make_float4(0.f, 0.f, 0.f, 0.f);
  for (; i < n4; i += st) p[i] = z;
}

__global__ void scatter_edges(const int* __restrict__ ei, int E, int n, float* __restrict__ A) {
  int e = blockIdx.x * blockDim.x + threadIdx.x;
  if (e < E) atomicAdd(&A[(size_t)ei[e] * n + ei[E + e]], 1.0f);
}

__global__ void diag_fix(float* __restrict__ A, int n) {
  int i = blockIdx.x * blockDim.x + threadIdx.x;
  if (i < n) { size_t id = (size_t)i * n + i; if (A[id] == 0.f) A[id] = 2.0f; }
}

__global__ void diag_set(float* __restrict__ A, int n, float v) {
  int i = blockIdx.x * blockDim.x + threadIdx.x;
  if (i < n) A[(size_t)i * n + i] = v;
}

__global__ void fill_i32(int* __restrict__ p, int n, int v) {
  int i = blockIdx.x * blockDim.x + threadIdx.x;
  if (i < n) p[i] = v;
}

__global__ void scatter_rank(const int* __restrict__ perm, int k, int* __restrict__ rank) {
  int j = blockIdx.x * blockDim.x + threadIdx.x;
  if (j < k) rank[perm[j]] = j;
}

// partial column sums (exact: small non-negative ints)
__global__ void col_deg_partial(const float* __restrict__ A, int n, float* __restrict__ deg) {
  int c = blockIdx.x * 256 + threadIdx.x;
  int j0 = blockIdx.y * 128;
  float s = 0.f;
#pragma unroll 4
  for (int j = 0; j < 128; ++j) s += A[(size_t)(j0 + j) * n + c];
  atomicAdd(&deg[c], s);
}

__global__ void deg_to_dinv(const float* __restrict__ deg, int n, float* __restrict__ dinv) {
  int i = blockIdx.x * blockDim.x + threadIdx.x;
  if (i < n) { float d = deg[i]; dinv[i] = (d > 0.f) ? 1.0f / sqrtf(d) : 0.f; }
}

// score[i] = tanh(dot(x[i,:], p) / ||p||), one wave per node
__global__ void node_scores(const float* __restrict__ x, const float* __restrict__ p,
                            int n, float* __restrict__ sc) {
  int wave = threadIdx.x >> 6;
  int lane = threadIdx.x & 63;
  int node = blockIdx.x * 4 + wave;
  if (node >= n) return;
  float4 pv = ((const float4*)p)[lane];
  float4 xv = ((const float4*)(x + (size_t)node * CH))[lane];
  float dot = xv.x * pv.x + xv.y * pv.y + xv.z * pv.z + xv.w * pv.w;
  float pn  = pv.x * pv.x + pv.y * pv.y + pv.z * pv.z + pv.w * pv.w;
  for (int off = 32; off; off >>= 1) {
    dot += __shfl_down(dot, off);
    pn  += __shfl_down(pn, off);
  }
  if (lane == 0) sc[node] = tanhf(dot / sqrtf(pn));
}

// bitonic sort (desc score, asc index tiebreak == jax.lax.top_k), n in {2048,4096}
__global__ __launch_bounds__(1024) void topk_sort(const float* __restrict__ sc, int n, int k,
                                                  int* __restrict__ perm, float* __restrict__ vals) {
  __shared__ float ss[4096];
  __shared__ int   si[4096];
  int tid = threadIdx.x;
  for (int i = tid; i < n; i += 1024) { ss[i] = sc[i]; si[i] = i; }
  __syncthreads();
  for (int size = 2; size <= n; size <<= 1) {
    for (int stride = size >> 1; stride > 0; stride >>= 1) {
      for (int i = tid; i < n; i += 1024) {
        int j = i ^ stride;
        if (j > i) {
          float a = ss[i], b = ss[j];
          int ia = si[i], ib = si[j];
          bool up = ((i & size) == 0);
          bool pj = (b > a) || (b == a && ib < ia);
          if (up ? pj : !pj) { ss[i] = b; ss[j] = a; si[i] = ib; si[j] = ia; }
        }
      }
      __syncthreads();
    }
  }
  for (int i = tid; i < k; i += 1024) { perm[i] = si[i]; vals[i] = ss[i]; }
}

// xo[i,:] = x[perm[i],:] * vals[i]
__global__ void pool_x(const float* __restrict__ x, const int* __restrict__ perm,
                       const float* __restrict__ vals, float* __restrict__ xo) {
  int i = blockIdx.x, c = threadIdx.x;
  xo[(size_t)i * CH + c] = x[(size_t)perm[i] * CH + c] * vals[i];
}

// ---------------- transpose / gather prep (fp32 -> bf16) ----------------

// O[m][0:n] = bf16(A[perm[m]][0:n]) — coalesced row gather + convert
__global__ void rowgather_cvt(const float* __restrict__ A, const int* __restrict__ perm,
                              int n, ushort* __restrict__ O) {
  int m = blockIdx.y;
  int k4 = (blockIdx.x * 256 + threadIdx.x) * 4;
  float4 v = *(const float4*)&A[(size_t)perm[m] * n + k4];
  ushort4 o;
  o.x = f2bf(v.x); o.y = f2bf(v.y); o.z = f2bf(v.z); o.w = f2bf(v.w);
  *(ushort4*)&O[(size_t)m * n + k4] = o;
}

// rank != nullptr: for cols j with rank[j]>=0, O[rank[j]][0:n] = bf16(A[0:n][j])
// rank == nullptr: full transpose  O[j][0:n] = bf16(A[0:n][j])
__global__ __launch_bounds__(256) void transpose_gather_cvt(
    const float* __restrict__ In, const int* __restrict__ rank,
    int n, ushort* __restrict__ O) {
  __shared__ float t[64][65];
  __shared__ int rk[64];
  int j0 = blockIdx.x * 64, i0 = blockIdx.y * 64;
  int tx = threadIdx.x & 63, ty4 = threadIdx.x >> 6;
#pragma unroll
  for (int r = 0; r < 64; r += 4)
    t[ty4 + r][tx] = In[(size_t)(i0 + ty4 + r) * n + j0 + tx];
  if (threadIdx.x < 64) rk[threadIdx.x] = rank ? rank[j0 + threadIdx.x] : (j0 + threadIdx.x);
  __syncthreads();
#pragma unroll
  for (int r = 0; r < 64; r += 4) {
    int c = ty4 + r;
    int rr = rk[c];
    if (rr >= 0) O[(size_t)rr * n + i0 + tx] = f2bf(t[tx][c]);
  }
}

// ---------------- bf16 MFMA augment GEMM: C[m][n] = sum_k Arow[m][k]*Brow[n][k] ----------------
__global__ __launch_bounds__(256) void mfma_augment(const ushort* __restrict__ Arow,
                                                    const ushort* __restrict__ Brow,
                                                    float* __restrict__ C, int Msz, int K) {
  __shared__ ushort As[128][72];
  __shared__ ushort Bs[128][72];
  const int tid = threadIdx.x;
  const int wave = tid >> 6, lane = tid & 63;
  const int wm = (wave & 1) * 64, wn = (wave >> 1) * 64;
  const int m0 = blockIdx.x * 128, n0 = blockIdx.y * 128;
  const int lrow = lane & 15;
  const int kq = (lane >> 4) * 8;
  f32x4 acc[4][4] = {};

  for (int kt = 0; kt < K; kt += 64) {
    __syncthreads();
#pragma unroll
    for (int r = 0; r < 4; ++r) {
      int c = tid + r * 256;
      int row = c >> 3, ks = (c & 7) * 8;
      *(uint4*)&As[row][ks] = *(const uint4*)&Arow[(size_t)(m0 + row) * K + kt + ks];
      *(uint4*)&Bs[row][ks] = *(const uint4*)&Brow[(size_t)(n0 + row) * K + kt + ks];
    }
    __syncthreads();
#pragma unroll
    for (int ks = 0; ks < 2; ++ks) {
      short8 af[4], bf[4];
#pragma unroll
      for (int t = 0; t < 4; ++t) {
        af[t] = *(const short8*)&As[wm + t * 16 + lrow][ks * 32 + kq];
        bf[t] = *(const short8*)&Bs[wn + t * 16 + lrow][ks * 32 + kq];
      }
#pragma unroll
      for (int mt = 0; mt < 4; ++mt)
#pragma unroll
        for (int nt = 0; nt < 4; ++nt)
          acc[mt][nt] = __builtin_amdgcn_mfma_f32_16x16x32_bf16(af[mt], bf[nt], acc[mt][nt], 0, 0, 0);
    }
  }

  const int crow = (lane >> 4) * 4, ccol = lane & 15;
#pragma unroll
  for (int mt = 0; mt < 4; ++mt)
#pragma unroll
    for (int nt = 0; nt < 4; ++nt) {
      int gm = m0 + wm + mt * 16 + crow;
      int gn = n0 + wn + nt * 16 + ccol;
#pragma unroll
      for (int r = 0; r < 4; ++r) {
        float v = acc[mt][nt][r];
        C[(size_t)(gm + r) * Msz + gn] = (gm + r == gn) ? 0.f : v;
      }
    }
}

// ---------------- bf16 MFMA aggregation: Cacc[m][c] += sum_k At[m][k]*Gt[c][k] ----------------
// tile 128(M) x 64(C), BK=64, split-K via blockIdx.z (chunk Ks), fp32 atomic accumulate
__global__ __launch_bounds__(256) void mfma_agg(const ushort* __restrict__ At,
                                                const ushort* __restrict__ Gt,
                                                float* __restrict__ Cacc, int K, int Ks) {
  __shared__ ushort As[128][72];
  __shared__ ushort Bs[64][72];
  const int tid = threadIdx.x;
  const int wave = tid >> 6, lane = tid & 63;
  const int wm = (wave & 1) * 64, wn = (wave >> 1) * 32;
  const int m0 = blockIdx.x * 128, n0 = blockIdx.y * 64;
  const int k0 = blockIdx.z * Ks;
  const int lrow = lane & 15;
  const int kq = (lane >> 4) * 8;
  f32x4 acc[4][2] = {};

  for (int kt = k0; kt < k0 + Ks; kt += 64) {
    __syncthreads();
#pragma unroll
    for (int r = 0; r < 4; ++r) {
      int c = tid + r * 256;
      int row = c >> 3, ks = (c & 7) * 8;
      *(uint4*)&As[row][ks] = *(const uint4*)&At[(size_t)(m0 + row) * K + kt + ks];
    }
#pragma unroll
    for (int r = 0; r < 2; ++r) {
      int c = tid + r * 256;
      int row = c >> 3, ks = (c & 7) * 8;
      *(uint4*)&Bs[row][ks] = *(const uint4*)&Gt[(size_t)(n0 + row) * K + kt + ks];
    }
    __syncthreads();
#pragma unroll
    for (int ks = 0; ks < 2; ++ks) {
      short8 af[4], bf[2];
#pragma unroll
      for (int t = 0; t < 4; ++t)
        af[t] = *(const short8*)&As[wm + t * 16 + lrow][ks * 32 + kq];
#pragma unroll
      for (int t = 0; t < 2; ++t)
        bf[t] = *(const short8*)&Bs[wn + t * 16 + lrow][ks * 32 + kq];
#pragma unroll
      for (int mt = 0; mt < 4; ++mt)
#pragma unroll
        for (int nt = 0; nt < 2; ++nt)
          acc[mt][nt] = __builtin_amdgcn_mfma_f32_16x16x32_bf16(af[mt], bf[nt], acc[mt][nt], 0, 0, 0);
    }
  }

  const int crow = (lane >> 4) * 4, ccol = lane & 15;
#pragma unroll
  for (int mt = 0; mt < 4; ++mt)
#pragma unroll
    for (int nt = 0; nt < 2; ++nt) {
      int gm = m0 + wm + mt * 16 + crow;
      int gn = n0 + wn + nt * 16 + ccol;
#pragma unroll
      for (int r = 0; r < 4; ++r)
        atomicAdd(&Cacc[(size_t)(gm + r) * CH + gn], acc[mt][nt][r]);
    }
}

// xo[m][c] = relu(dinv[m]*Cacc[m][c] + bias[c]); one float4 per thread
__global__ void agg_epilogue(const float* __restrict__ Cacc, const float* __restrict__ dinv,
                             const float* __restrict__ bias, float* __restrict__ xo) {
  int idx = blockIdx.x * 256 + threadIdx.x;   // float4 index
  int c4 = idx & (CH / 4 - 1);
  int m = idx >> 6;
  float4 v = ((const float4*)Cacc)[idx];
  float4 b = ((const float4*)bias)[c4];
  float s = dinv[m];
  v.x = fmaxf(fmaf(v.x, s, b.x), 0.f);
  v.y = fmaxf(fmaf(v.y, s, b.y), 0.f);
  v.z = fmaxf(fmaf(v.z, s, b.z), 0.f);
  v.w = fmaxf(fmaf(v.w, s, b.w), 0.f);
  ((float4*)xo)[idx] = v;
}

// ---------------- fp32 xW GEMM (64x64 tile) -> writes Gt[n][m] = bf16(dinv[m]*(x@W)[m][n]) ----------------
__global__ __launch_bounds__(256) void xw_gemm(const float* __restrict__ Am,
                                               const float* __restrict__ Bm,
                                               ushort* __restrict__ Gt,
                                               int M, const float* __restrict__ dinv) {
  __shared__ float As[16][64];
  __shared__ float Bs[16][64];
  const int tid = threadIdx.x;
  const int m0 = blockIdx.x * 64, n0 = blockIdx.y * 64;
  float acc[4][4] = {{0.f}};
  const int tm = tid & 15, tn = tid >> 4;

  for (int kt = 0; kt < CH; kt += 16) {
    __syncthreads();
    {
      int mm = tid >> 2, kq = (tid & 3) * 4;
      float4 v = *(const float4*)(Am + (size_t)(m0 + mm) * CH + kt + kq);
      As[kq + 0][mm] = v.x; As[kq + 1][mm] = v.y; As[kq + 2][mm] = v.z; As[kq + 3][mm] = v.w;
    }
#pragma unroll
    for (int r = 0; r < 4; ++r) {
      int idx = tid + r * 256;
      int kk = idx >> 6, nn = idx & 63;
      Bs[kk][nn] = Bm[(size_t)(kt + kk) * CH + (n0 + nn)];
    }
    __syncthreads();
#pragma unroll
    for (int kk = 0; kk < 16; ++kk) {
      float4 a = *(const float4*)&As[kk][tm * 4];
      float4 b = *(const float4*)&Bs[kk][tn * 4];
      acc[0][0] = fmaf(a.x, b.x, acc[0][0]);
      acc[0][1] = fmaf(a.x, b.y, acc[0][1]);
      acc[0][2] = fmaf(a.x, b.z, acc[0][2]);
      acc[0][3] = fmaf(a.x, b.w, acc[0][3]);
      acc[1][0] = fmaf(a.y, b.x, acc[1][0]);
      acc[1][1] = fmaf(a.y, b.y, acc[1][1]);
      acc[1][2] = fmaf(a.y, b.z, acc[1][2]);
      acc[1][3] = fmaf(a.y, b.w, acc[1][3]);
      acc[2][0] = fmaf(a.z, b.x, acc[2][0]);
      acc[2][1] = fmaf(a.z, b.y, acc[2][1]);
      acc[2][2] = fmaf(a.z, b.z, acc[2][2]);
      acc[2][3] = fmaf(a.z, b.w, acc[2][3]);
      acc[3][0] = fmaf(a.w, b.x, acc[3][0]);
      acc[3][1] = fmaf(a.w, b.y, acc[3][1]);
      acc[3][2] = fmaf(a.w, b.z, acc[3][2]);
      acc[3][3] = fmaf(a.w, b.w, acc[3][3]);
    }
  }

#pragma unroll
  for (int ii = 0; ii < 4; ++ii) {
    int m = m0 + tm * 4 + ii;
    float s = dinv[m];
#pragma unroll
    for (int jj = 0; jj < 4; ++jj) {
      int n = n0 + tn * 4 + jj;
      Gt[(size_t)n * M + m] = f2bf(s * acc[ii][jj]);
    }
  }
}

// mean over rows -> normalize -> logits -> log_softmax
__global__ __launch_bounds__(256) void finalize(const float* __restrict__ x2, int nr,
                                                const float* __restrict__ wc,
                                                const float* __restrict__ bc,
                                                float* __restrict__ out) {
  __shared__ float semb[256];
  __shared__ float red[256];
  __shared__ float slog[16];
  int c = threadIdx.x;
  float s = 0.f;
  for (int r = 0; r < nr; ++r) s += x2[(size_t)r * CH + c];
  float emb = s / (float)nr;
  red[c] = emb * emb;
  __syncthreads();
  for (int off = 128; off; off >>= 1) {
    if (c < off) red[c] += red[c + off];
    __syncthreads();
  }
  float denom = fmaxf(sqrtf(red[0]), 1e-12f);
  float en = emb / denom;
  semb[c] = en;
  out[c] = en;
  __syncthreads();
  if (c < 10) {
    float l = bc[c];
    for (int t = 0; t < CH; ++t) l = fmaf(semb[t], wc[c * CH + t], l);
    slog[c] = l;
  }
  __syncthreads();
  if (c == 0) {
    float mx = slog[0];
    for (int j = 1; j < 10; ++j) mx = fmaxf(mx, slog[j]);
    float se = 0.f;
    for (int j = 0; j < 10; ++j) se += expf(slog[j] - mx);
    float lse = mx + logf(se);
    for (int j = 0; j < 10; ++j) out[CH + j] = slog[j] - lse;
  }
}

// ---------------- orchestration ----------------

extern "C" void kernel_launch(void* const* d_in, const int* in_sizes, int n_in,
                              void* d_out, int out_size, void* d_ws, size_t ws_size,
                              hipStream_t stream) {
  const float* x  = (const float*)d_in[0];
  const int*   ei = (const int*)d_in[1];
  const float* w0 = (const float*)d_in[2];
  const float* b0 = (const float*)d_in[3];
  const float* w1 = (const float*)d_in[4];
  const float* b1 = (const float*)d_in[5];
  const float* w2 = (const float*)d_in[6];
  const float* b2 = (const float*)d_in[7];
  const float* p1 = (const float*)d_in[8];
  const float* p2 = (const float*)d_in[9];
  const float* wc = (const float*)d_in[10];
  const float* bc = (const float*)d_in[11];
  float* out = (float*)d_out;
  const int N0 = 4096, K1 = 2048, K2 = 1024;
  int E = in_sizes[1] / 2;

  float* W = (float*)d_ws;
  size_t off = 0;
  float* A    = W + off; off += (size_t)N0 * N0;
  float* Pa   = W + off; off += (size_t)K1 * K1;
  float* Pb   = W + off; off += (size_t)K2 * K2;
  // shared bf16 region: At/Pat/Pbt (transposed adj) OR Arow+Brow (augment operands)
  ushort* REG = (ushort*)(W + off); off += (size_t)K1 * N0;  // 16.78M ushorts = 8.39M floats
  ushort* At   = REG;
  ushort* Arow = REG;
  ushort* Brow = REG + (size_t)K1 * N0;
  float* x0   = W + off; off += (size_t)N0 * CH;
  float* Cacc = W + off; off += (size_t)N0 * CH;
  ushort* Gt  = (ushort*)(W + off); off += (size_t)N0 * CH / 2;
  float* xp  = W + off; off += (size_t)K1 * CH;
  float* x1  = W + off; off += (size_t)K1 * CH;
  float* x2  = W + off; off += (size_t)K2 * CH;
  float* sc  = W + off; off += 4096;
  float* vals = W + off; off += 4096;
  float* deg  = W + off; off += 4096;
  float* dinv = W + off; off += 4096;
  int* perm1 = (int*)(W + off); off += 4096;
  int* perm2 = (int*)(W + off); off += 4096;
  int* rank = (int*)sc;  // sc dead after topk_sort

  // ---- build adjacency ----
  fill_zero4<<<2048, 256, 0, stream>>>((float4*)A, (size_t)N0 * N0 / 4);
  scatter_edges<<<(E + 255) / 256, 256, 0, stream>>>(ei, E, N0, A);

  // ---- GCN 0 ----
  diag_fix<<<N0 / 256, 256, 0, stream>>>(A, N0);
  transpose_gather_cvt<<<dim3(N0 / 64, N0 / 64), 256, 0, stream>>>(A, nullptr, N0, At);
  fill_zero4<<<4, 256, 0, stream>>>((float4*)deg, N0 / 4);
  col_deg_partial<<<dim3(N0 / 256, N0 / 128), 256, 0, stream>>>(A, N0, deg);
  deg_to_dinv<<<N0 / 256, 256, 0, stream>>>(deg, N0, dinv);
  xw_gemm<<<dim3(N0 / 64, CH / 64), 256, 0, stream>>>(x, w0, Gt, N0, dinv);
  fill_zero4<<<256, 256, 0, stream>>>((float4*)Cacc, (size_t)N0 * CH / 4);
  mfma_agg<<<dim3(N0 / 128, CH / 64, 4), 256, 0, stream>>>(At, Gt, Cacc, N0, N0 / 4);
  agg_epilogue<<<N0 / 4, 256, 0, stream>>>(Cacc, dinv, b0, x0);

  // ---- pool 1 ----
  node_scores<<<N0 / 4, 256, 0, stream>>>(x0, p1, N0, sc);
  topk_sort<<<1, 1024, 0, stream>>>(sc, N0, K1, perm1, vals);

  // ---- augment L1 (bf16 MFMA, exact) ----
  diag_set<<<N0 / 256, 256, 0, stream>>>(A, N0, 1.0f);
  fill_i32<<<N0 / 256, 256, 0, stream>>>(rank, N0, -1);
  scatter_rank<<<K1 / 256, 256, 0, stream>>>(perm1, K1, rank);
  rowgather_cvt<<<dim3(N0 / 1024, K1), 256, 0, stream>>>(A, perm1, N0, Arow);
  transpose_gather_cvt<<<dim3(N0 / 64, N0 / 64), 256, 0, stream>>>(A, rank, N0, Brow);
  mfma_augment<<<dim3(K1 / 128, K1 / 128), 256, 0, stream>>>(Arow, Brow, Pa, K1, N0);
  pool_x<<<K1, 256, 0, stream>>>(x0, perm1, vals, xp);

  // ---- GCN 1 ----
  diag_fix<<<K1 / 256, 256, 0, stream>>>(Pa, K1);
  transpose_gather_cvt<<<dim3(K1 / 64, K1 / 64), 256, 0, stream>>>(Pa, nullptr, K1, At);
  fill_zero4<<<1, 256, 0, stream>>>((float4*)deg, K1 / 4);
  col_deg_partial<<<dim3(K1 / 256, K1 / 128), 256, 0, stream>>>(Pa, K1, deg);
  deg_to_dinv<<<K1 / 256, 256, 0, stream>>>(deg, K1, dinv);
  xw_gemm<<<dim3(K1 / 64, CH / 64), 256, 0, stream>>>(xp, w1, Gt, K1, dinv);
  fill_zero4<<<128, 256, 0, stream>>>((float4*)Cacc, (size_t)K1 * CH / 4);
  mfma_agg<<<dim3(K1 / 128, CH / 64, 4), 256, 0, stream>>>(At, Gt, Cacc, K1, K1 / 4);
  agg_epilogue<<<K1 / 4, 256, 0, stream>>>(Cacc, dinv, b1, x1);

  // ---- pool 2 ----
  node_scores<<<K1 / 4, 256, 0, stream>>>(x1, p2, K1, sc);
  topk_sort<<<1, 1024, 0, stream>>>(sc, K1, K2, perm2, vals);

  // ---- augment L2 ----
  diag_set<<<K1 / 256, 256, 0, stream>>>(Pa, K1, 1.0f);
  fill_i32<<<K1 / 256, 256, 0, stream>>>(rank, K1, -1);
  scatter_rank<<<K2 / 256, 256, 0, stream>>>(perm2, K2, rank);
  rowgather_cvt<<<dim3(K1 / 1024, K2), 256, 0, stream>>>(Pa, perm2, K1, Arow);
  transpose_gather_cvt<<<dim3(K1 / 64, K1 / 64), 256, 0, stream>>>(Pa, rank, K1, Brow);
  mfma_augment<<<dim3(K2 / 128, K2 / 128), 256, 0, stream>>>(Arow, Brow, Pb, K2, K1);
  pool_x<<<K2, 256, 0, stream>>>(x1, perm2, vals, xp);

  // ---- GCN 2 ----
  diag_fix<<<K2 / 256, 256, 0, stream>>>(Pb, K2);
  transpose_gather_cvt<<<dim3(K2 / 64, K2 / 64), 256, 0, stream>>>(Pb, nullptr, K2, At);
  fill_zero4<<<1, 256, 0, stream>>>((float4*)deg, K2 / 4);
  col_deg_partial<<<dim3(K2 / 256, K2 / 128), 256, 0, stream>>>(Pb, K2, deg);
  deg_to_dinv<<<K2 / 256, 256, 0, stream>>>(deg, K2, dinv);
  xw_gemm<<<dim3(K2 / 64, CH / 64), 256, 0, stream>>>(xp, w2, Gt, K2, dinv);
  fill_zero4<<<64, 256, 0, stream>>>((float4*)Cacc, (size_t)K2 * CH / 4);
  mfma_agg<<<dim3(K2 / 128, CH / 64, 4), 256, 0, stream>>>(At, Gt, Cacc, K2, K2 / 4);
  agg_epilogue<<<K2 / 4, 256, 0, stream>>>(Cacc, dinv, b2, x2);

  // ---- readout ----
  finalize<<<1, 256, 0, stream>>>(x2, K2, wc, bc, out);
}

// Round 5
// 569.179 us; speedup vs baseline: 5.9087x; 1.4054x over previous
//
#include <hip/hip_runtime.h>
#include <math.h>

#define CH 256

typedef short short8 __attribute__((ext_vector_type(8)));
typedef float f32x4 __attribute__((ext_vector_type(4)));

// f32 -> bf16 bits (RNE); adjacency values are small ints, exact
__device__ inline ushort f2bf(float f) {
  unsigned u = __float_as_uint(f);
  unsigned r = (u + 0x7FFFu + ((u >> 16) & 1u)) >> 16;
  return (ushort)r;
}

// ---------------- utility kernels ----------------

__global__ void fill_zero4(float4* __restrict__ p, size_t n4) {
  size_t i = (size_t)blockIdx.x * blockDim.x + threadIdx.x;
  size_t st = (size_t)gridDim.x * blockDim.x;
  float4 z = make_float4(0.f, 0.f, 0.f, 0.f);
  for (; i < n4; i += st) p[i] = z;
}

__global__ void scatter_edges(const int* __restrict__ ei, int E, int n, float* __restrict__ A) {
  int e = blockIdx.x * blockDim.x + threadIdx.x;
  if (e < E) atomicAdd(&A[(size_t)ei[e] * n + ei[E + e]], 1.0f);
}

__global__ void diag_fix(float* __restrict__ A, int n) {
  int i = blockIdx.x * blockDim.x + threadIdx.x;
  if (i < n) { size_t id = (size_t)i * n + i; if (A[id] == 0.f) A[id] = 2.0f; }
}

__global__ void diag_set(float* __restrict__ A, int n, float v) {
  int i = blockIdx.x * blockDim.x + threadIdx.x;
  if (i < n) A[(size_t)i * n + i] = v;
}

__global__ void fill_i32(int* __restrict__ p, int n, int v) {
  int i = blockIdx.x * blockDim.x + threadIdx.x;
  if (i < n) p[i] = v;
}

__global__ void scatter_rank(const int* __restrict__ perm, int k, int* __restrict__ rank) {
  int j = blockIdx.x * blockDim.x + threadIdx.x;
  if (j < k) rank[perm[j]] = j;
}

// partial column sums (exact: small non-negative ints)
__global__ void col_deg_partial(const float* __restrict__ A, int n, float* __restrict__ deg) {
  int c = blockIdx.x * 256 + threadIdx.x;
  int j0 = blockIdx.y * 128;
  float s = 0.f;
#pragma unroll 4
  for (int j = 0; j < 128; ++j) s += A[(size_t)(j0 + j) * n + c];
  atomicAdd(&deg[c], s);
}

__global__ void deg_to_dinv(const float* __restrict__ deg, int n, float* __restrict__ dinv) {
  int i = blockIdx.x * blockDim.x + threadIdx.x;
  if (i < n) { float d = deg[i]; dinv[i] = (d > 0.f) ? 1.0f / sqrtf(d) : 0.f; }
}

// score[i] = tanh(dot(x[i,:], p) / ||p||), one wave per node
__global__ void node_scores(const float* __restrict__ x, const float* __restrict__ p,
                            int n, float* __restrict__ sc) {
  int wave = threadIdx.x >> 6;
  int lane = threadIdx.x & 63;
  int node = blockIdx.x * 4 + wave;
  if (node >= n) return;
  float4 pv = ((const float4*)p)[lane];
  float4 xv = ((const float4*)(x + (size_t)node * CH))[lane];
  float dot = xv.x * pv.x + xv.y * pv.y + xv.z * pv.z + xv.w * pv.w;
  float pn  = pv.x * pv.x + pv.y * pv.y + pv.z * pv.z + pv.w * pv.w;
  for (int off = 32; off; off >>= 1) {
    dot += __shfl_down(dot, off);
    pn  += __shfl_down(pn, off);
  }
  if (lane == 0) sc[node] = tanhf(dot / sqrtf(pn));
}

// bitonic sort (desc score, asc index tiebreak == jax.lax.top_k), n in {2048,4096}
__global__ __launch_bounds__(1024) void topk_sort(const float* __restrict__ sc, int n, int k,
                                                  int* __restrict__ perm, float* __restrict__ vals) {
  __shared__ float ss[4096];
  __shared__ int   si[4096];
  int tid = threadIdx.x;
  for (int i = tid; i < n; i += 1024) { ss[i] = sc[i]; si[i] = i; }
  __syncthreads();
  for (int size = 2; size <= n; size <<= 1) {
    for (int stride = size >> 1; stride > 0; stride >>= 1) {
      for (int i = tid; i < n; i += 1024) {
        int j = i ^ stride;
        if (j > i) {
          float a = ss[i], b = ss[j];
          int ia = si[i], ib = si[j];
          bool up = ((i & size) == 0);
          bool pj = (b > a) || (b == a && ib < ia);
          if (up ? pj : !pj) { ss[i] = b; ss[j] = a; si[i] = ib; si[j] = ia; }
        }
      }
      __syncthreads();
    }
  }
  for (int i = tid; i < k; i += 1024) { perm[i] = si[i]; vals[i] = ss[i]; }
}

// xo[i,:] = x[perm[i],:] * vals[i]
__global__ void pool_x(const float* __restrict__ x, const int* __restrict__ perm,
                       const float* __restrict__ vals, float* __restrict__ xo) {
  int i = blockIdx.x, c = threadIdx.x;
  xo[(size_t)i * CH + c] = x[(size_t)perm[i] * CH + c] * vals[i];
}

// ---------------- transpose / gather prep (fp32 -> bf16) ----------------

// O[m][0:n] = bf16(A[perm[m]][0:n]) — coalesced row gather + convert
__global__ void rowgather_cvt(const float* __restrict__ A, const int* __restrict__ perm,
                              int n, ushort* __restrict__ O) {
  int m = blockIdx.y;
  int k4 = (blockIdx.x * 256 + threadIdx.x) * 4;
  float4 v = *(const float4*)&A[(size_t)perm[m] * n + k4];
  ushort4 o;
  o.x = f2bf(v.x); o.y = f2bf(v.y); o.z = f2bf(v.z); o.w = f2bf(v.w);
  *(ushort4*)&O[(size_t)m * n + k4] = o;
}

// rank != nullptr: for cols j with rank[j]>=0, O[rank[j]][0:n] = bf16(A[0:n][j])
// rank == nullptr: full transpose  O[j][0:n] = bf16(A[0:n][j])
__global__ __launch_bounds__(256) void transpose_gather_cvt(
    const float* __restrict__ In, const int* __restrict__ rank,
    int n, ushort* __restrict__ O) {
  __shared__ float t[64][65];
  __shared__ int rk[64];
  int j0 = blockIdx.x * 64, i0 = blockIdx.y * 64;
  int tx = threadIdx.x & 63, ty4 = threadIdx.x >> 6;
#pragma unroll
  for (int r = 0; r < 64; r += 4)
    t[ty4 + r][tx] = In[(size_t)(i0 + ty4 + r) * n + j0 + tx];
  if (threadIdx.x < 64) rk[threadIdx.x] = rank ? rank[j0 + threadIdx.x] : (j0 + threadIdx.x);
  __syncthreads();
#pragma unroll
  for (int r = 0; r < 64; r += 4) {
    int c = ty4 + r;
    int rr = rk[c];
    if (rr >= 0) O[(size_t)rr * n + i0 + tx] = f2bf(t[tx][c]);
  }
}

// ---------------- bf16 MFMA augment GEMM: C[m][n] = sum_k Arow[m][k]*Brow[n][k] ----------------
__global__ __launch_bounds__(256) void mfma_augment(const ushort* __restrict__ Arow,
                                                    const ushort* __restrict__ Brow,
                                                    float* __restrict__ C, int Msz, int K) {
  __shared__ ushort As[128][72];
  __shared__ ushort Bs[128][72];
  const int tid = threadIdx.x;
  const int wave = tid >> 6, lane = tid & 63;
  const int wm = (wave & 1) * 64, wn = (wave >> 1) * 64;
  const int m0 = blockIdx.x * 128, n0 = blockIdx.y * 128;
  const int lrow = lane & 15;
  const int kq = (lane >> 4) * 8;
  f32x4 acc[4][4] = {};

  for (int kt = 0; kt < K; kt += 64) {
    __syncthreads();
#pragma unroll
    for (int r = 0; r < 4; ++r) {
      int c = tid + r * 256;
      int row = c >> 3, ks = (c & 7) * 8;
      *(uint4*)&As[row][ks] = *(const uint4*)&Arow[(size_t)(m0 + row) * K + kt + ks];
      *(uint4*)&Bs[row][ks] = *(const uint4*)&Brow[(size_t)(n0 + row) * K + kt + ks];
    }
    __syncthreads();
#pragma unroll
    for (int ks = 0; ks < 2; ++ks) {
      short8 af[4], bf[4];
#pragma unroll
      for (int t = 0; t < 4; ++t) {
        af[t] = *(const short8*)&As[wm + t * 16 + lrow][ks * 32 + kq];
        bf[t] = *(const short8*)&Bs[wn + t * 16 + lrow][ks * 32 + kq];
      }
#pragma unroll
      for (int mt = 0; mt < 4; ++mt)
#pragma unroll
        for (int nt = 0; nt < 4; ++nt)
          acc[mt][nt] = __builtin_amdgcn_mfma_f32_16x16x32_bf16(af[mt], bf[nt], acc[mt][nt], 0, 0, 0);
    }
  }

  const int crow = (lane >> 4) * 4, ccol = lane & 15;
#pragma unroll
  for (int mt = 0; mt < 4; ++mt)
#pragma unroll
    for (int nt = 0; nt < 4; ++nt) {
      int gm = m0 + wm + mt * 16 + crow;
      int gn = n0 + wn + nt * 16 + ccol;
#pragma unroll
      for (int r = 0; r < 4; ++r) {
        float v = acc[mt][nt][r];
        C[(size_t)(gm + r) * Msz + gn] = (gm + r == gn) ? 0.f : v;
      }
    }
}

// ---------------- bf16 MFMA aggregation: Cacc[m][c] += sum_k At[m][k]*Gt[c][k] ----------------
// tile 128(M) x 64(C), BK=64, split-K via blockIdx.z (chunk Ks), fp32 atomic accumulate
__global__ __launch_bounds__(256) void mfma_agg(const ushort* __restrict__ At,
                                                const ushort* __restrict__ Gt,
                                                float* __restrict__ Cacc, int K, int Ks) {
  __shared__ ushort As[128][72];
  __shared__ ushort Bs[64][72];
  const int tid = threadIdx.x;
  const int wave = tid >> 6, lane = tid & 63;
  const int wm = (wave & 1) * 64, wn = (wave >> 1) * 32;
  const int m0 = blockIdx.x * 128, n0 = blockIdx.y * 64;
  const int k0 = blockIdx.z * Ks;
  const int lrow = lane & 15;
  const int kq = (lane >> 4) * 8;
  f32x4 acc[4][2] = {};

  for (int kt = k0; kt < k0 + Ks; kt += 64) {
    __syncthreads();
#pragma unroll
    for (int r = 0; r < 4; ++r) {
      int c = tid + r * 256;
      int row = c >> 3, ks = (c & 7) * 8;
      *(uint4*)&As[row][ks] = *(const uint4*)&At[(size_t)(m0 + row) * K + kt + ks];
    }
#pragma unroll
    for (int r = 0; r < 2; ++r) {
      int c = tid + r * 256;
      int row = c >> 3, ks = (c & 7) * 8;
      *(uint4*)&Bs[row][ks] = *(const uint4*)&Gt[(size_t)(n0 + row) * K + kt + ks];
    }
    __syncthreads();
#pragma unroll
    for (int ks = 0; ks < 2; ++ks) {
      short8 af[4], bf[2];
#pragma unroll
      for (int t = 0; t < 4; ++t)
        af[t] = *(const short8*)&As[wm + t * 16 + lrow][ks * 32 + kq];
#pragma unroll
      for (int t = 0; t < 2; ++t)
        bf[t] = *(const short8*)&Bs[wn + t * 16 + lrow][ks * 32 + kq];
#pragma unroll
      for (int mt = 0; mt < 4; ++mt)
#pragma unroll
        for (int nt = 0; nt < 2; ++nt)
          acc[mt][nt] = __builtin_amdgcn_mfma_f32_16x16x32_bf16(af[mt], bf[nt], acc[mt][nt], 0, 0, 0);
    }
  }

  const int crow = (lane >> 4) * 4, ccol = lane & 15;
#pragma unroll
  for (int mt = 0; mt < 4; ++mt)
#pragma unroll
    for (int nt = 0; nt < 2; ++nt) {
      int gm = m0 + wm + mt * 16 + crow;
      int gn = n0 + wn + nt * 16 + ccol;
#pragma unroll
      for (int r = 0; r < 4; ++r)
        atomicAdd(&Cacc[(size_t)(gm + r) * CH + gn], acc[mt][nt][r]);
    }
}

// xo[m][c] = relu(dinv[m]*Cacc[m][c] + bias[c]); one float4 per thread
__global__ void agg_epilogue(const float* __restrict__ Cacc, const float* __restrict__ dinv,
                             const float* __restrict__ bias, float* __restrict__ xo) {
  int idx = blockIdx.x * 256 + threadIdx.x;   // float4 index
  int c4 = idx & (CH / 4 - 1);
  int m = idx >> 6;
  float4 v = ((const float4*)Cacc)[idx];
  float4 b = ((const float4*)bias)[c4];
  float s = dinv[m];
  v.x = fmaxf(fmaf(v.x, s, b.x), 0.f);
  v.y = fmaxf(fmaf(v.y, s, b.y), 0.f);
  v.z = fmaxf(fmaf(v.z, s, b.z), 0.f);
  v.w = fmaxf(fmaf(v.w, s, b.w), 0.f);
  ((float4*)xo)[idx] = v;
}

// ---------------- fp32 xW GEMM (64x64 tile) -> writes Gt[n][m] = bf16(dinv[m]*(x@W)[m][n]) ----------------
__global__ __launch_bounds__(256) void xw_gemm(const float* __restrict__ Am,
                                               const float* __restrict__ Bm,
                                               ushort* __restrict__ Gt,
                                               int M, const float* __restrict__ dinv) {
  __shared__ float As[16][64];
  __shared__ float Bs[16][64];
  const int tid = threadIdx.x;
  const int m0 = blockIdx.x * 64, n0 = blockIdx.y * 64;
  float acc[4][4] = {{0.f}};
  const int tm = tid & 15, tn = tid >> 4;

  for (int kt = 0; kt < CH; kt += 16) {
    __syncthreads();
    {
      int mm = tid >> 2, kq = (tid & 3) * 4;
      float4 v = *(const float4*)(Am + (size_t)(m0 + mm) * CH + kt + kq);
      As[kq + 0][mm] = v.x; As[kq + 1][mm] = v.y; As[kq + 2][mm] = v.z; As[kq + 3][mm] = v.w;
    }
#pragma unroll
    for (int r = 0; r < 4; ++r) {
      int idx = tid + r * 256;
      int kk = idx >> 6, nn = idx & 63;
      Bs[kk][nn] = Bm[(size_t)(kt + kk) * CH + (n0 + nn)];
    }
    __syncthreads();
#pragma unroll
    for (int kk = 0; kk < 16; ++kk) {
      float4 a = *(const float4*)&As[kk][tm * 4];
      float4 b = *(const float4*)&Bs[kk][tn * 4];
      acc[0][0] = fmaf(a.x, b.x, acc[0][0]);
      acc[0][1] = fmaf(a.x, b.y, acc[0][1]);
      acc[0][2] = fmaf(a.x, b.z, acc[0][2]);
      acc[0][3] = fmaf(a.x, b.w, acc[0][3]);
      acc[1][0] = fmaf(a.y, b.x, acc[1][0]);
      acc[1][1] = fmaf(a.y, b.y, acc[1][1]);
      acc[1][2] = fmaf(a.y, b.z, acc[1][2]);
      acc[1][3] = fmaf(a.y, b.w, acc[1][3]);
      acc[2][0] = fmaf(a.z, b.x, acc[2][0]);
      acc[2][1] = fmaf(a.z, b.y, acc[2][1]);
      acc[2][2] = fmaf(a.z, b.z, acc[2][2]);
      acc[2][3] = fmaf(a.z, b.w, acc[2][3]);
      acc[3][0] = fmaf(a.w, b.x, acc[3][0]);
      acc[3][1] = fmaf(a.w, b.y, acc[3][1]);
      acc[3][2] = fmaf(a.w, b.z, acc[3][2]);
      acc[3][3] = fmaf(a.w, b.w, acc[3][3]);
    }
  }

#pragma unroll
  for (int ii = 0; ii < 4; ++ii) {
    int m = m0 + tm * 4 + ii;
    float s = dinv[m];
#pragma unroll
    for (int jj = 0; jj < 4; ++jj) {
      int n = n0 + tn * 4 + jj;
      Gt[(size_t)n * M + m] = f2bf(s * acc[ii][jj]);
    }
  }
}

// ---------------- readout (2-stage) ----------------

// partial column sums of x2 into macc[256] (atomic, 16 rows per block)
__global__ void mean_partial(const float* __restrict__ x2, float* __restrict__ macc) {
  int c = threadIdx.x;
  int j0 = blockIdx.x * 16;
  float s = 0.f;
#pragma unroll
  for (int j = 0; j < 16; ++j) s += x2[(size_t)(j0 + j) * CH + c];
  atomicAdd(&macc[c], s);
}

// macc -> mean -> normalize -> logits -> log_softmax
__global__ __launch_bounds__(256) void finalize2(const float* __restrict__ macc, int nr,
                                                 const float* __restrict__ wc,
                                                 const float* __restrict__ bc,
                                                 float* __restrict__ out) {
  __shared__ float semb[256];
  __shared__ float red[256];
  __shared__ float slog[16];
  int c = threadIdx.x;
  float emb = macc[c] / (float)nr;
  red[c] = emb * emb;
  __syncthreads();
  for (int off = 128; off; off >>= 1) {
    if (c < off) red[c] += red[c + off];
    __syncthreads();
  }
  float denom = fmaxf(sqrtf(red[0]), 1e-12f);
  float en = emb / denom;
  semb[c] = en;
  out[c] = en;
  __syncthreads();
  if (c < 10) {
    float l = bc[c];
    for (int t = 0; t < CH; ++t) l = fmaf(semb[t], wc[c * CH + t], l);
    slog[c] = l;
  }
  __syncthreads();
  if (c == 0) {
    float mx = slog[0];
    for (int j = 1; j < 10; ++j) mx = fmaxf(mx, slog[j]);
    float se = 0.f;
    for (int j = 0; j < 10; ++j) se += expf(slog[j] - mx);
    float lse = mx + logf(se);
    for (int j = 0; j < 10; ++j) out[CH + j] = slog[j] - lse;
  }
}

// ---------------- orchestration ----------------

extern "C" void kernel_launch(void* const* d_in, const int* in_sizes, int n_in,
                              void* d_out, int out_size, void* d_ws, size_t ws_size,
                              hipStream_t stream) {
  const float* x  = (const float*)d_in[0];
  const int*   ei = (const int*)d_in[1];
  const float* w0 = (const float*)d_in[2];
  const float* b0 = (const float*)d_in[3];
  const float* w1 = (const float*)d_in[4];
  const float* b1 = (const float*)d_in[5];
  const float* w2 = (const float*)d_in[6];
  const float* b2 = (const float*)d_in[7];
  const float* p1 = (const float*)d_in[8];
  const float* p2 = (const float*)d_in[9];
  const float* wc = (const float*)d_in[10];
  const float* bc = (const float*)d_in[11];
  float* out = (float*)d_out;
  const int N0 = 4096, K1 = 2048, K2 = 1024;
  int E = in_sizes[1] / 2;

  float* W = (float*)d_ws;
  size_t off = 0;
  float* A    = W + off; off += (size_t)N0 * N0;
  float* Pa   = W + off; off += (size_t)K1 * K1;
  float* Pb   = W + off; off += (size_t)K2 * K2;
  // shared bf16 region: At (transposed adj) OR Arow+Brow (augment operands)
  ushort* REG = (ushort*)(W + off); off += (size_t)K1 * N0;
  ushort* At   = REG;
  ushort* Arow = REG;
  ushort* Brow = REG + (size_t)K1 * N0;
  float* x0   = W + off; off += (size_t)N0 * CH;
  float* Cacc = W + off; off += (size_t)N0 * CH;
  ushort* Gt  = (ushort*)(W + off); off += (size_t)N0 * CH / 2;
  float* xp  = W + off; off += (size_t)K1 * CH;
  float* x1  = W + off; off += (size_t)K1 * CH;
  float* x2  = W + off; off += (size_t)K2 * CH;
  float* sc  = W + off; off += 4096;
  float* vals = W + off; off += 4096;
  float* deg  = W + off; off += 4096;
  float* dinv = W + off; off += 4096;
  float* macc = W + off; off += 256;
  int* perm1 = (int*)(W + off); off += 4096;
  int* perm2 = (int*)(W + off); off += 4096;
  int* rank = (int*)sc;  // sc dead after topk_sort

  // ---- build adjacency ----
  fill_zero4<<<2048, 256, 0, stream>>>((float4*)A, (size_t)N0 * N0 / 4);
  scatter_edges<<<(E + 255) / 256, 256, 0, stream>>>(ei, E, N0, A);

  // ---- GCN 0 ----
  diag_fix<<<N0 / 256, 256, 0, stream>>>(A, N0);
  transpose_gather_cvt<<<dim3(N0 / 64, N0 / 64), 256, 0, stream>>>(A, nullptr, N0, At);
  fill_zero4<<<4, 256, 0, stream>>>((float4*)deg, N0 / 4);
  col_deg_partial<<<dim3(N0 / 256, N0 / 128), 256, 0, stream>>>(A, N0, deg);
  deg_to_dinv<<<N0 / 256, 256, 0, stream>>>(deg, N0, dinv);
  xw_gemm<<<dim3(N0 / 64, CH / 64), 256, 0, stream>>>(x, w0, Gt, N0, dinv);
  fill_zero4<<<256, 256, 0, stream>>>((float4*)Cacc, (size_t)N0 * CH / 4);
  mfma_agg<<<dim3(N0 / 128, CH / 64, 4), 256, 0, stream>>>(At, Gt, Cacc, N0, N0 / 4);
  agg_epilogue<<<N0 / 4, 256, 0, stream>>>(Cacc, dinv, b0, x0);

  // ---- pool 1 ----
  node_scores<<<N0 / 4, 256, 0, stream>>>(x0, p1, N0, sc);
  topk_sort<<<1, 1024, 0, stream>>>(sc, N0, K1, perm1, vals);

  // ---- augment L1 (bf16 MFMA, exact) ----
  diag_set<<<N0 / 256, 256, 0, stream>>>(A, N0, 1.0f);
  fill_i32<<<N0 / 256, 256, 0, stream>>>(rank, N0, -1);
  scatter_rank<<<K1 / 256, 256, 0, stream>>>(perm1, K1, rank);
  rowgather_cvt<<<dim3(N0 / 1024, K1), 256, 0, stream>>>(A, perm1, N0, Arow);
  transpose_gather_cvt<<<dim3(N0 / 64, N0 / 64), 256, 0, stream>>>(A, rank, N0, Brow);
  mfma_augment<<<dim3(K1 / 128, K1 / 128), 256, 0, stream>>>(Arow, Brow, Pa, K1, N0);
  pool_x<<<K1, 256, 0, stream>>>(x0, perm1, vals, xp);

  // ---- GCN 1 ----
  diag_fix<<<K1 / 256, 256, 0, stream>>>(Pa, K1);
  transpose_gather_cvt<<<dim3(K1 / 64, K1 / 64), 256, 0, stream>>>(Pa, nullptr, K1, At);
  fill_zero4<<<1, 256, 0, stream>>>((float4*)deg, K1 / 4);
  col_deg_partial<<<dim3(K1 / 256, K1 / 128), 256, 0, stream>>>(Pa, K1, deg);
  deg_to_dinv<<<K1 / 256, 256, 0, stream>>>(deg, K1, dinv);
  xw_gemm<<<dim3(K1 / 64, CH / 64), 256, 0, stream>>>(xp, w1, Gt, K1, dinv);
  fill_zero4<<<128, 256, 0, stream>>>((float4*)Cacc, (size_t)K1 * CH / 4);
  mfma_agg<<<dim3(K1 / 128, CH / 64, 4), 256, 0, stream>>>(At, Gt, Cacc, K1, K1 / 4);
  agg_epilogue<<<K1 / 4, 256, 0, stream>>>(Cacc, dinv, b1, x1);

  // ---- pool 2 ----
  node_scores<<<K1 / 4, 256, 0, stream>>>(x1, p2, K1, sc);
  topk_sort<<<1, 1024, 0, stream>>>(sc, K1, K2, perm2, vals);

  // ---- augment L2 ----
  diag_set<<<K1 / 256, 256, 0, stream>>>(Pa, K1, 1.0f);
  fill_i32<<<K1 / 256, 256, 0, stream>>>(rank, K1, -1);
  scatter_rank<<<K2 / 256, 256, 0, stream>>>(perm2, K2, rank);
  rowgather_cvt<<<dim3(K1 / 1024, K2), 256, 0, stream>>>(Pa, perm2, K1, Arow);
  transpose_gather_cvt<<<dim3(K1 / 64, K1 / 64), 256, 0, stream>>>(Pa, rank, K1, Brow);
  mfma_augment<<<dim3(K2 / 128, K2 / 128), 256, 0, stream>>>(Arow, Brow, Pb, K2, K1);
  pool_x<<<K2, 256, 0, stream>>>(x1, perm2, vals, xp);

  // ---- GCN 2 ----
  diag_fix<<<K2 / 256, 256, 0, stream>>>(Pb, K2);
  transpose_gather_cvt<<<dim3(K2 / 64, K2 / 64), 256, 0, stream>>>(Pb, nullptr, K2, At);
  fill_zero4<<<1, 256, 0, stream>>>((float4*)deg, K2 / 4);
  col_deg_partial<<<dim3(K2 / 256, K2 / 128), 256, 0, stream>>>(Pb, K2, deg);
  deg_to_dinv<<<K2 / 256, 256, 0, stream>>>(deg, K2, dinv);
  xw_gemm<<<dim3(K2 / 64, CH / 64), 256, 0, stream>>>(xp, w2, Gt, K2, dinv);
  fill_zero4<<<64, 256, 0, stream>>>((float4*)Cacc, (size_t)K2 * CH / 4);
  mfma_agg<<<dim3(K2 / 128, CH / 64, 4), 256, 0, stream>>>(At, Gt, Cacc, K2, K2 / 4);
  agg_epilogue<<<K2 / 4, 256, 0, stream>>>(Cacc, dinv, b2, x2);

  // ---- readout ----
  fill_zero4<<<1, 64, 0, stream>>>((float4*)macc, 64);
  mean_partial<<<K2 / 16, 256, 0, stream>>>(x2, macc);
  finalize2<<<1, 256, 0, stream>>>(macc, K2, wc, bc, out);
}

// Round 6
// 500.826 us; speedup vs baseline: 6.7151x; 1.1365x over previous
//
#include <hip/hip_runtime.h>
#include <math.h>

#define CH 256

typedef short short8 __attribute__((ext_vector_type(8)));
typedef float f32x4 __attribute__((ext_vector_type(4)));

// f32 -> bf16 bits (RNE); adjacency values are small ints, exact
__device__ inline ushort f2bf(float f) {
  unsigned u = __float_as_uint(f);
  unsigned r = (u + 0x7FFFu + ((u >> 16) & 1u)) >> 16;
  return (ushort)r;
}

// ---------------- build ----------------

__global__ void scatter_edges(const int* __restrict__ ei, int E, int n, float* __restrict__ A) {
  int e = blockIdx.x * blockDim.x + threadIdx.x;
  if (e < E) atomicAdd(&A[(size_t)ei[e] * n + ei[E + e]], 1.0f);
}

// ---------------- fused transpose + diag rule + column-degree ----------------
// DIAGMODE 0: diag v==0 -> 2.0 (GCN rule on raw A); DIAGMODE 1: diag forced 2.0 (post-augment)
// Writes At[j][i] = bf16(v(i,j)) and deg[j] += column sums (exact small ints).
template <int DIAGMODE>
__global__ __launch_bounds__(256) void transpose_deg(const float* __restrict__ In, int n,
                                                     ushort* __restrict__ O, float* __restrict__ deg) {
  __shared__ float t[64][65];
  int j0 = blockIdx.x * 64, i0 = blockIdx.y * 64;
  int tx = threadIdx.x & 63, ty4 = threadIdx.x >> 6;
  float s = 0.f;
#pragma unroll
  for (int r = 0; r < 64; r += 4) {
    int gi = i0 + ty4 + r, gj = j0 + tx;
    float v = In[(size_t)gi * n + gj];
    if (gi == gj) v = (DIAGMODE == 1) ? 2.0f : ((v != 0.f) ? v : 2.0f);
    t[ty4 + r][tx] = v;
    s += v;
  }
  atomicAdd(&deg[j0 + tx], s);
  __syncthreads();
#pragma unroll
  for (int r = 0; r < 64; r += 4) {
    int c = ty4 + r;
    O[(size_t)(j0 + c) * n + i0 + tx] = f2bf(t[tx][c]);
  }
}

// ---------------- top-k: bitonic sort on packed u64 (desc score, asc index) ----------------
__global__ __launch_bounds__(1024) void topk_sort(const float* __restrict__ sc, int n, int k,
                                                  int* __restrict__ perm, float* __restrict__ vals) {
  __shared__ unsigned long long key[4096];
  int tid = threadIdx.x;
  for (int i = tid; i < n; i += 1024) {
    unsigned u = __float_as_uint(sc[i]);
    u = (u & 0x80000000u) ? ~u : (u | 0x80000000u);   // order-preserving flip
    key[i] = ((unsigned long long)u << 32) | (0xFFFFFFFFu - (unsigned)i);
  }
  __syncthreads();
  for (int size = 2; size <= n; size <<= 1) {
    for (int stride = size >> 1; stride > 0; stride >>= 1) {
      for (int i = tid; i < n; i += 1024) {
        int j = i ^ stride;
        if (j > i) {
          unsigned long long ka = key[i], kb = key[j];
          bool up = ((i & size) == 0);
          bool pj = kb > ka;                          // j should precede i (descending)
          if (up ? pj : !pj) { key[i] = kb; key[j] = ka; }
        }
      }
      __syncthreads();
    }
  }
  for (int i = tid; i < k; i += 1024) {
    unsigned long long kk = key[i];
    unsigned u = (unsigned)(kk >> 32);
    u = (u & 0x80000000u) ? (u & 0x7FFFFFFFu) : ~u;
    perm[i] = (int)(0xFFFFFFFFu - (unsigned)(kk & 0xFFFFFFFFu));
    vals[i] = __uint_as_float(u);
  }
}

// xo[i,:] = x[perm[i],:] * vals[i]
__global__ void pool_x(const float* __restrict__ x, const int* __restrict__ perm,
                       const float* __restrict__ vals, float* __restrict__ xo) {
  int i = blockIdx.x, c = threadIdx.x;
  xo[(size_t)i * CH + c] = x[(size_t)perm[i] * CH + c] * vals[i];
}

// ---------------- augment operand gathers (diag forced to 1 inline) ----------------

// O[m][0:n] = bf16(A[perm[m]][0:n]), entry at col==perm[m] -> 1.0
__global__ void rowgather_cvt(const float* __restrict__ A, const int* __restrict__ perm,
                              int n, ushort* __restrict__ O) {
  int m = blockIdx.y;
  int src = perm[m];
  int k4 = (blockIdx.x * 256 + threadIdx.x) * 4;
  float4 v = *(const float4*)&A[(size_t)src * n + k4];
  if (src >= k4 && src < k4 + 4) ((float*)&v)[src - k4] = 1.0f;
  ushort4 o;
  o.x = f2bf(v.x); o.y = f2bf(v.y); o.z = f2bf(v.z); o.w = f2bf(v.w);
  *(ushort4*)&O[(size_t)m * n + k4] = o;
}

// O[m][0:n] = At[perm[m]][0:n] (bf16 copy), entry at col==perm[m] -> 1.0
__global__ void rowgather_bf16(const ushort* __restrict__ At, const int* __restrict__ perm,
                               int n, ushort* __restrict__ O) {
  int m = blockIdx.y;
  int src = perm[m];
  int k8 = (blockIdx.x * 256 + threadIdx.x) * 8;
  uint4 v = *(const uint4*)&At[(size_t)src * n + k8];
  if (src >= k8 && src < k8 + 8) ((ushort*)&v)[src - k8] = 0x3F80;  // bf16(1.0)
  *(uint4*)&O[(size_t)m * n + k8] = v;
}

// ---------------- bf16 MFMA augment GEMM: C[m][n] = sum_k Arow[m][k]*Brow[n][k] ----------------
// tile 128(M) x 64(N), full K, plain stores (diag handled by downstream overrides)
__global__ __launch_bounds__(256) void mfma_augment(const ushort* __restrict__ Arow,
                                                    const ushort* __restrict__ Brow,
                                                    float* __restrict__ C, int Msz, int K) {
  __shared__ ushort As[128][72];
  __shared__ ushort Bs[64][72];
  const int tid = threadIdx.x;
  const int wave = tid >> 6, lane = tid & 63;
  const int wm = (wave & 1) * 64, wn = (wave >> 1) * 32;
  const int m0 = blockIdx.x * 128, n0 = blockIdx.y * 64;
  const int lrow = lane & 15;
  const int kq = (lane >> 4) * 8;
  f32x4 acc[4][2] = {};

  for (int kt = 0; kt < K; kt += 64) {
    __syncthreads();
#pragma unroll
    for (int r = 0; r < 4; ++r) {
      int c = tid + r * 256;
      int row = c >> 3, ks = (c & 7) * 8;
      *(uint4*)&As[row][ks] = *(const uint4*)&Arow[(size_t)(m0 + row) * K + kt + ks];
    }
#pragma unroll
    for (int r = 0; r < 2; ++r) {
      int c = tid + r * 256;
      int row = c >> 3, ks = (c & 7) * 8;
      *(uint4*)&Bs[row][ks] = *(const uint4*)&Brow[(size_t)(n0 + row) * K + kt + ks];
    }
    __syncthreads();
#pragma unroll
    for (int ks = 0; ks < 2; ++ks) {
      short8 af[4], bf[2];
#pragma unroll
      for (int t = 0; t < 4; ++t)
        af[t] = *(const short8*)&As[wm + t * 16 + lrow][ks * 32 + kq];
#pragma unroll
      for (int t = 0; t < 2; ++t)
        bf[t] = *(const short8*)&Bs[wn + t * 16 + lrow][ks * 32 + kq];
#pragma unroll
      for (int mt = 0; mt < 4; ++mt)
#pragma unroll
        for (int nt = 0; nt < 2; ++nt)
          acc[mt][nt] = __builtin_amdgcn_mfma_f32_16x16x32_bf16(af[mt], bf[nt], acc[mt][nt], 0, 0, 0);
    }
  }

  const int crow = (lane >> 4) * 4, ccol = lane & 15;
#pragma unroll
  for (int mt = 0; mt < 4; ++mt)
#pragma unroll
    for (int nt = 0; nt < 2; ++nt) {
      int gm = m0 + wm + mt * 16 + crow;
      int gn = n0 + wn + nt * 16 + ccol;
#pragma unroll
      for (int r = 0; r < 4; ++r)
        C[(size_t)(gm + r) * Msz + gn] = acc[mt][nt][r];
    }
}

// ---------------- bf16 MFMA aggregation: Cacc[m][c] += sum_k At[m][k]*Gt[c][k] ----------------
__global__ __launch_bounds__(256) void mfma_agg(const ushort* __restrict__ At,
                                                const ushort* __restrict__ Gt,
                                                float* __restrict__ Cacc, int K, int Ks) {
  __shared__ ushort As[128][72];
  __shared__ ushort Bs[64][72];
  const int tid = threadIdx.x;
  const int wave = tid >> 6, lane = tid & 63;
  const int wm = (wave & 1) * 64, wn = (wave >> 1) * 32;
  const int m0 = blockIdx.x * 128, n0 = blockIdx.y * 64;
  const int k0 = blockIdx.z * Ks;
  const int lrow = lane & 15;
  const int kq = (lane >> 4) * 8;
  f32x4 acc[4][2] = {};

  for (int kt = k0; kt < k0 + Ks; kt += 64) {
    __syncthreads();
#pragma unroll
    for (int r = 0; r < 4; ++r) {
      int c = tid + r * 256;
      int row = c >> 3, ks = (c & 7) * 8;
      *(uint4*)&As[row][ks] = *(const uint4*)&At[(size_t)(m0 + row) * K + kt + ks];
    }
#pragma unroll
    for (int r = 0; r < 2; ++r) {
      int c = tid + r * 256;
      int row = c >> 3, ks = (c & 7) * 8;
      *(uint4*)&Bs[row][ks] = *(const uint4*)&Gt[(size_t)(n0 + row) * K + kt + ks];
    }
    __syncthreads();
#pragma unroll
    for (int ks = 0; ks < 2; ++ks) {
      short8 af[4], bf[2];
#pragma unroll
      for (int t = 0; t < 4; ++t)
        af[t] = *(const short8*)&As[wm + t * 16 + lrow][ks * 32 + kq];
#pragma unroll
      for (int t = 0; t < 2; ++t)
        bf[t] = *(const short8*)&Bs[wn + t * 16 + lrow][ks * 32 + kq];
#pragma unroll
      for (int mt = 0; mt < 4; ++mt)
#pragma unroll
        for (int nt = 0; nt < 2; ++nt)
          acc[mt][nt] = __builtin_amdgcn_mfma_f32_16x16x32_bf16(af[mt], bf[nt], acc[mt][nt], 0, 0, 0);
    }
  }

  const int crow = (lane >> 4) * 4, ccol = lane & 15;
#pragma unroll
  for (int mt = 0; mt < 4; ++mt)
#pragma unroll
    for (int nt = 0; nt < 2; ++nt) {
      int gm = m0 + wm + mt * 16 + crow;
      int gn = n0 + wn + nt * 16 + ccol;
#pragma unroll
      for (int r = 0; r < 4; ++r)
        atomicAdd(&Cacc[(size_t)(gm + r) * CH + gn], acc[mt][nt][r]);
    }
}

// xo[m][c]=relu(dinv[m]*Cacc+bias); optional fused score: sc[m]=tanh(dot(xo[m],p)/||p||)
// one wave per row (64 lanes x float4 = 256 ch)
__global__ void agg_epilogue(const float* __restrict__ Cacc, const float* __restrict__ deg,
                             const float* __restrict__ bias, float* __restrict__ xo,
                             const float* __restrict__ p, float* __restrict__ sc) {
  int idx = blockIdx.x * 256 + threadIdx.x;
  int c4 = idx & 63;
  int m = idx >> 6;
  float d = deg[m];
  float s = (d > 0.f) ? 1.0f / sqrtf(d) : 0.f;
  float4 v = ((const float4*)Cacc)[idx];
  float4 b = ((const float4*)bias)[c4];
  v.x = fmaxf(fmaf(v.x, s, b.x), 0.f);
  v.y = fmaxf(fmaf(v.y, s, b.y), 0.f);
  v.z = fmaxf(fmaf(v.z, s, b.z), 0.f);
  v.w = fmaxf(fmaf(v.w, s, b.w), 0.f);
  ((float4*)xo)[idx] = v;
  if (p) {
    float4 pv = ((const float4*)p)[c4];
    float dot = v.x * pv.x + v.y * pv.y + v.z * pv.z + v.w * pv.w;
    float pn  = pv.x * pv.x + pv.y * pv.y + pv.z * pv.z + pv.w * pv.w;
    for (int off = 32; off; off >>= 1) {
      dot += __shfl_down(dot, off);
      pn  += __shfl_down(pn, off);
    }
    if ((threadIdx.x & 63) == 0) sc[m] = tanhf(dot / sqrtf(pn));
  }
}

// ---------------- fp32 xW GEMM -> Gt[n][m] = bf16(dinv[m]*(x@W)[m][n]) ----------------
__global__ __launch_bounds__(256) void xw_gemm(const float* __restrict__ Am,
                                               const float* __restrict__ Bm,
                                               ushort* __restrict__ Gt,
                                               int M, const float* __restrict__ deg) {
  __shared__ float As[16][64];
  __shared__ float Bs[16][64];
  const int tid = threadIdx.x;
  const int m0 = blockIdx.x * 64, n0 = blockIdx.y * 64;
  float acc[4][4] = {{0.f}};
  const int tm = tid & 15, tn = tid >> 4;

  for (int kt = 0; kt < CH; kt += 16) {
    __syncthreads();
    {
      int mm = tid >> 2, kq = (tid & 3) * 4;
      float4 v = *(const float4*)(Am + (size_t)(m0 + mm) * CH + kt + kq);
      As[kq + 0][mm] = v.x; As[kq + 1][mm] = v.y; As[kq + 2][mm] = v.z; As[kq + 3][mm] = v.w;
    }
#pragma unroll
    for (int r = 0; r < 4; ++r) {
      int idx = tid + r * 256;
      int kk = idx >> 6, nn = idx & 63;
      Bs[kk][nn] = Bm[(size_t)(kt + kk) * CH + (n0 + nn)];
    }
    __syncthreads();
#pragma unroll
    for (int kk = 0; kk < 16; ++kk) {
      float4 a = *(const float4*)&As[kk][tm * 4];
      float4 b = *(const float4*)&Bs[kk][tn * 4];
      acc[0][0] = fmaf(a.x, b.x, acc[0][0]);
      acc[0][1] = fmaf(a.x, b.y, acc[0][1]);
      acc[0][2] = fmaf(a.x, b.z, acc[0][2]);
      acc[0][3] = fmaf(a.x, b.w, acc[0][3]);
      acc[1][0] = fmaf(a.y, b.x, acc[1][0]);
      acc[1][1] = fmaf(a.y, b.y, acc[1][1]);
      acc[1][2] = fmaf(a.y, b.z, acc[1][2]);
      acc[1][3] = fmaf(a.y, b.w, acc[1][3]);
      acc[2][0] = fmaf(a.z, b.x, acc[2][0]);
      acc[2][1] = fmaf(a.z, b.y, acc[2][1]);
      acc[2][2] = fmaf(a.z, b.z, acc[2][2]);
      acc[2][3] = fmaf(a.z, b.w, acc[2][3]);
      acc[3][0] = fmaf(a.w, b.x, acc[3][0]);
      acc[3][1] = fmaf(a.w, b.y, acc[3][1]);
      acc[3][2] = fmaf(a.w, b.z, acc[3][2]);
      acc[3][3] = fmaf(a.w, b.w, acc[3][3]);
    }
  }

#pragma unroll
  for (int ii = 0; ii < 4; ++ii) {
    int m = m0 + tm * 4 + ii;
    float d = deg[m];
    float s = (d > 0.f) ? 1.0f / sqrtf(d) : 0.f;
#pragma unroll
    for (int jj = 0; jj < 4; ++jj) {
      int n = n0 + tn * 4 + jj;
      Gt[(size_t)n * M + m] = f2bf(s * acc[ii][jj]);
    }
  }
}

// ---------------- readout ----------------

__global__ void mean_partial(const float* __restrict__ x2, float* __restrict__ macc) {
  int c = threadIdx.x;
  int j0 = blockIdx.x * 16;
  float s = 0.f;
#pragma unroll
  for (int j = 0; j < 16; ++j) s += x2[(size_t)(j0 + j) * CH + c];
  atomicAdd(&macc[c], s);
}

__global__ __launch_bounds__(256) void finalize2(const float* __restrict__ macc, int nr,
                                                 const float* __restrict__ wc,
                                                 const float* __restrict__ bc,
                                                 float* __restrict__ out) {
  __shared__ float semb[256];
  __shared__ float red[256];
  __shared__ float slog[16];
  int c = threadIdx.x;
  float emb = macc[c] / (float)nr;
  red[c] = emb * emb;
  __syncthreads();
  for (int off = 128; off; off >>= 1) {
    if (c < off) red[c] += red[c + off];
    __syncthreads();
  }
  float denom = fmaxf(sqrtf(red[0]), 1e-12f);
  float en = emb / denom;
  semb[c] = en;
  out[c] = en;
  __syncthreads();
  if (c < 10) {
    float l = bc[c];
    for (int t = 0; t < CH; ++t) l = fmaf(semb[t], wc[c * CH + t], l);
    slog[c] = l;
  }
  __syncthreads();
  if (c == 0) {
    float mx = slog[0];
    for (int j = 1; j < 10; ++j) mx = fmaxf(mx, slog[j]);
    float se = 0.f;
    for (int j = 0; j < 10; ++j) se += expf(slog[j] - mx);
    float lse = mx + logf(se);
    for (int j = 0; j < 10; ++j) out[CH + j] = slog[j] - lse;
  }
}

// ---------------- orchestration ----------------

extern "C" void kernel_launch(void* const* d_in, const int* in_sizes, int n_in,
                              void* d_out, int out_size, void* d_ws, size_t ws_size,
                              hipStream_t stream) {
  const float* x  = (const float*)d_in[0];
  const int*   ei = (const int*)d_in[1];
  const float* w0 = (const float*)d_in[2];
  const float* b0 = (const float*)d_in[3];
  const float* w1 = (const float*)d_in[4];
  const float* b1 = (const float*)d_in[5];
  const float* w2 = (const float*)d_in[6];
  const float* b2 = (const float*)d_in[7];
  const float* p1 = (const float*)d_in[8];
  const float* p2 = (const float*)d_in[9];
  const float* wc = (const float*)d_in[10];
  const float* bc = (const float*)d_in[11];
  float* out = (float*)d_out;
  const int N0 = 4096, K1 = 2048, K2 = 1024;
  int E = in_sizes[1] / 2;

  float* W = (float*)d_ws;
  size_t off = 0;
  float* A    = W + off; off += (size_t)N0 * N0;                  // fp32 adj; later reused as Brow
  float* Pa   = W + off; off += (size_t)K1 * K1;
  float* Pb   = W + off; off += (size_t)K2 * K2;
  ushort* At  = (ushort*)(W + off); off += (size_t)N0 * N0 / 2;   // bf16 transposed adj (per level)
  ushort* Arow = (ushort*)(W + off); off += (size_t)K1 * N0 / 2;  // bf16 gathered rows
  ushort* Brow = (ushort*)A;                                      // aliases A (dead by then)
  float* x0   = W + off; off += (size_t)N0 * CH;
  float* Cacc = W + off; off += (size_t)N0 * CH;
  ushort* Gt  = (ushort*)(W + off); off += (size_t)N0 * CH / 2;
  float* xp  = W + off; off += (size_t)K1 * CH;
  float* x1  = W + off; off += (size_t)K1 * CH;
  float* x2  = W + off; off += (size_t)K2 * CH;
  float* sc  = W + off; off += 4096;
  float* vals = W + off; off += 4096;
  float* deg  = W + off; off += 4096;
  float* macc = W + off; off += 256;
  int* perm1 = (int*)(W + off); off += 4096;
  int* perm2 = (int*)(W + off); off += 4096;

  // ---- build adjacency ----
  hipMemsetAsync(A, 0, (size_t)N0 * N0 * 4, stream);
  scatter_edges<<<(E + 255) / 256, 256, 0, stream>>>(ei, E, N0, A);

  // ---- GCN 0 ----
  hipMemsetAsync(deg, 0, N0 * 4, stream);
  transpose_deg<0><<<dim3(N0 / 64, N0 / 64), 256, 0, stream>>>(A, N0, At, deg);
  xw_gemm<<<dim3(N0 / 64, CH / 64), 256, 0, stream>>>(x, w0, Gt, N0, deg);
  hipMemsetAsync(Cacc, 0, (size_t)N0 * CH * 4, stream);
  mfma_agg<<<dim3(N0 / 128, CH / 64, 4), 256, 0, stream>>>(At, Gt, Cacc, N0, N0 / 4);
  agg_epilogue<<<N0 / 4, 256, 0, stream>>>(Cacc, deg, b0, x0, p1, sc);

  // ---- pool 1 ----
  topk_sort<<<1, 1024, 0, stream>>>(sc, N0, K1, perm1, vals);

  // ---- augment L1: Pa = (B@B)[perm1][:,perm1], B = A w/ diag 1 (bf16 MFMA, exact) ----
  rowgather_cvt<<<dim3(N0 / 1024, K1), 256, 0, stream>>>(A, perm1, N0, Arow);
  rowgather_bf16<<<dim3(N0 / 2048, K1), 256, 0, stream>>>(At, perm1, N0, Brow);
  mfma_augment<<<dim3(K1 / 128, K1 / 64), 256, 0, stream>>>(Arow, Brow, Pa, K1, N0);
  pool_x<<<K1, 256, 0, stream>>>(x0, perm1, vals, xp);

  // ---- GCN 1 ----
  hipMemsetAsync(deg, 0, K1 * 4, stream);
  transpose_deg<1><<<dim3(K1 / 64, K1 / 64), 256, 0, stream>>>(Pa, K1, At, deg);
  xw_gemm<<<dim3(K1 / 64, CH / 64), 256, 0, stream>>>(xp, w1, Gt, K1, deg);
  hipMemsetAsync(Cacc, 0, (size_t)K1 * CH * 4, stream);
  mfma_agg<<<dim3(K1 / 128, CH / 64, 4), 256, 0, stream>>>(At, Gt, Cacc, K1, K1 / 4);
  agg_epilogue<<<K1 / 4, 256, 0, stream>>>(Cacc, deg, b1, x1, p2, sc);

  // ---- pool 2 ----
  topk_sort<<<1, 1024, 0, stream>>>(sc, K1, K2, perm2, vals);

  // ---- augment L2 ----
  rowgather_cvt<<<dim3(K1 / 1024, K2), 256, 0, stream>>>(Pa, perm2, K1, Arow);
  rowgather_bf16<<<dim3(K1 / 2048, K2), 256, 0, stream>>>(At, perm2, K1, Brow);
  mfma_augment<<<dim3(K2 / 128, K2 / 64), 256, 0, stream>>>(Arow, Brow, Pb, K2, K1);
  pool_x<<<K2, 256, 0, stream>>>(x1, perm2, vals, xp);

  // ---- GCN 2 ----
  hipMemsetAsync(deg, 0, K2 * 4, stream);
  transpose_deg<1><<<dim3(K2 / 64, K2 / 64), 256, 0, stream>>>(Pb, K2, At, deg);
  xw_gemm<<<dim3(K2 / 64, CH / 64), 256, 0, stream>>>(xp, w2, Gt, K2, deg);
  hipMemsetAsync(Cacc, 0, (size_t)K2 * CH * 4, stream);
  mfma_agg<<<dim3(K2 / 128, CH / 64, 4), 256, 0, stream>>>(At, Gt, Cacc, K2, K2 / 4);
  agg_epilogue<<<K2 / 4, 256, 0, stream>>>(Cacc, deg, b2, x2, nullptr, nullptr);

  // ---- readout ----
  hipMemsetAsync(macc, 0, 256 * 4, stream);
  mean_partial<<<K2 / 16, 256, 0, stream>>>(x2, macc);
  finalize2<<<1, 256, 0, stream>>>(macc, K2, wc, bc, out);
}